// Round 6
// baseline (440.953 us; speedup 1.0000x reference)
//
#include <hip/hip_runtime.h>
#include <stdint.h>

// B=4, C=O=320, H=W=64 -> HW=4096, N2=32768 (dconv n<16384, h n>=16384),
// K=2880 (M pad 384 in Wr only), Kf=640.
// K-permutation: kk = g*72 + k*8 + cl, c = g*8+cl (g<40, k<9, cl<8); kkb=kk>>3=g*9+k.
// Xp (padded x): [g][b][py 66][px 66][cl 8] bf16; interior = x, halo = 0.
// Cc packed-8: elem(o,n2) at (o>>3)*32768*8 + n2*8 + (o&7).
// Wr K-major packed-8: elem(o,kk) at (kkb*384 + o)*8 + (kk&7). W2 likewise (Kf).
//
// Round 6: Sd im2col buffer ELIMINATED (was 94 MB write + 64 MB HBM read +
// a whole kernel). k_gemm's dconv-half B-tile is gathered+blended on the fly
// from Xp inside the GEMM (T14 issue-early/write-late):
//   per (row,px) unit: oU[k9,p] = u32 base offset into padded plane (halo
//   makes all 4 taps {base, +1px, +1row, +1row+1px} safe; OOB weights are 0),
//   oW[k9,p] = float4 weights. taps issued BEFORE the 40-MFMA cluster,
//   blend + ds_write AFTER it -> uses the gemm's idle VALU/VMEM slack.
//   recs for tile s+2 prefetched one step early (L2 latency cover).
// k_gather deleted. h-half staging, A-staging, MFMA body unchanged (r2 best).
//
// ws layout (bytes):
//   Cc 0..25,165,824 | Wr ..27,377,664 | W2 ..27,869,184 | oU ..28,164,096
//   oWt ..28,753,920 | hoffG ..28,758,016 | Xp ..39,909,376 (+1KB zero ext)

typedef __attribute__((ext_vector_type(4))) float f32x4;
typedef __attribute__((ext_vector_type(8))) short bf16x8;

typedef __attribute__((address_space(1))) const unsigned int uint_as1;
typedef __attribute__((address_space(3))) unsigned int uint_as3;

__device__ __forceinline__ void gl_lds16(const void* g, void* l) {
    __builtin_amdgcn_global_load_lds((uint_as1*)g, (uint_as3*)l, 16, 0, 0);
}

__device__ __forceinline__ unsigned short f2b(float f) {
    union { float f; uint32_t u; } v; v.f = f;
    uint32_t r = (v.u + 0x7FFFu + ((v.u >> 16) & 1u)) >> 16;
    return (unsigned short)r;
}
__device__ __forceinline__ float b2f(unsigned short h) {
    union { uint32_t u; float f; } v; v.u = ((uint32_t)h) << 16;
    return v.f;
}
__device__ __forceinline__ float b2f_lo(uint32_t u) {
    union { uint32_t u; float f; } v; v.u = u << 16;
    return v.f;
}
__device__ __forceinline__ float b2f_hi(uint32_t u) {
    union { uint32_t u; float f; } v; v.u = u & 0xFFFF0000u;
    return v.f;
}
__device__ __forceinline__ uint32_t pack2(float lo, float hi) {
    return (uint32_t)f2b(lo) | ((uint32_t)f2b(hi) << 16);
}

#define TAP(tv, wvx) \
    ac[0] += wvx * b2f_lo((uint32_t)tv.x); ac[1] += wvx * b2f_hi((uint32_t)tv.x); \
    ac[2] += wvx * b2f_lo((uint32_t)tv.y); ac[3] += wvx * b2f_hi((uint32_t)tv.y); \
    ac[4] += wvx * b2f_lo((uint32_t)tv.z); ac[5] += wvx * b2f_hi((uint32_t)tv.z); \
    ac[6] += wvx * b2f_lo((uint32_t)tv.w); ac[7] += wvx * b2f_hi((uint32_t)tv.w);

// ---------------------------------------------------------------------------
// Fused prep. [0,144) bilinear recs (oU base offset + oW weights);
// [144,684) Wr (ushort8 coalesced); [684,1644) W2; [1644,1646) hoffG;
// [1646,2327) zero Xp (+overflow extension).
__global__ __launch_bounds__(256) void k_prep(const float* __restrict__ off,
                                              const float* __restrict__ w,
                                              const float* __restrict__ wd,
                                              const float* __restrict__ wu,
                                              uint32_t* __restrict__ oU,
                                              float* __restrict__ oW,
                                              unsigned short* __restrict__ Wr,
                                              unsigned short* __restrict__ W2,
                                              int* __restrict__ hoffG,
                                              unsigned short* __restrict__ Xp)
{
    const int bx = blockIdx.x, tid = threadIdx.x;
    if (bx < 144) {
        int gid = bx * 256 + tid;                    // 9*4096 exact
        int k = gid >> 12;
        int p = gid & 4095;
        int i = p >> 6, j = p & 63;
        float dy = off[(2 * k) * 4096 + p];
        float dx = off[(2 * k + 1) * 4096 + p];
        float py = (float)(i - 1 + k / 3) + dy;
        float px = (float)(j - 1 + k % 3) + dx;
        float fy = floorf(py), fx = floorf(px);
        float wy = py - fy, wx = px - fx;
        fy = fminf(fmaxf(fy, -100.f), 100.f);
        fx = fminf(fmaxf(fx, -100.f), 100.f);
        int y0 = (int)fy, x0 = (int)fx;
        float vy0 = (y0 >= 0 && y0 < 64) ? 1.f : 0.f;
        float vy1 = (y0 >= -1 && y0 < 63) ? 1.f : 0.f;
        float vx0 = (x0 >= 0 && x0 < 64) ? 1.f : 0.f;
        float vx1 = (x0 >= -1 && x0 < 63) ? 1.f : 0.f;
        float w00 = (1.f - wy) * (1.f - wx) * vy0 * vx0;
        float w01 = (1.f - wy) * wx * vy0 * vx1;
        float w10 = wy * (1.f - wx) * vy1 * vx0;
        float w11 = wy * wx * vy1 * vx1;
        // Padded-plane base (halo absorbs OOB; all-OOB weights are 0 so any
        // in-range base is safe). Taps: base, +8, +528, +536 (ushort units).
        int iya = min(max(y0, -1), 64);
        int ixa = min(max(x0, -1), 64);
        oU[gid] = (uint32_t)(((iya + 1) * 66 + (ixa + 1)) * 8);
        oW[gid * 4 + 0] = w00;
        oW[gid * 4 + 1] = w01;
        oW[gid * 4 + 2] = w10;
        oW[gid * 4 + 3] = w11;
    } else if (bx < 684) {
        // Wr: one thread per (kkb,o), ushort8 coalesced store. 540*256 =
        // 138240 = 360*384 exact.
        int gid = (bx - 144) * 256 + tid;
        int kkb = gid / 384, o = gid - kkb * 384;
        int g = kkb / 9, k = kkb - g * 9;
        float v[8];
        #pragma unroll
        for (int cl = 0; cl < 8; ++cl) {
            int c = g * 8 + cl;
            v[cl] = (o < 320) ? w[((size_t)o * 320 + c) * 9 + k] : 0.f;
        }
        int4 st;
        st.x = (int)pack2(v[0], v[1]);
        st.y = (int)pack2(v[2], v[3]);
        st.z = (int)pack2(v[4], v[5]);
        st.w = (int)pack2(v[6], v[7]);
        *(int4*)(Wr + (size_t)gid * 8) = st;
    } else if (bx < 1644) {
        int gid = (bx - 684) * 256 + tid;            // 384*640 exact
        int o = gid / 640, kk2 = gid % 640;
        float acc = 0.f;
        if (o < 320) {
            for (int l = 0; l < 320; ++l)
                acc += wu[o * 320 + l] * wd[l * 640 + kk2];
        }
        W2[(size_t)((kk2 >> 3) * 384 + o) * 8 + (kk2 & 7)] = f2b(acc);
    } else if (bx < 1646) {
        int kkb = (bx - 1644) * 256 + tid;           // 360 entries
        if (kkb < 360) {
            int g = kkb / 9, k = kkb % 9;
            hoffG[kkb] = (g * 17424 + (k / 3) * 66 + (k % 3)) * 8; // ushort units
        }
    } else {
        // zero Xp: 696,960 int4 units + 64 extra (last-plane overflow row,
        // ensures 0-weight taps never read uninitialized bits -> no 0*NaN).
        int bz = bx - 1646;                          // 681 blocks
        #pragma unroll
        for (int j = 0; j < 4; ++j) {
            int u = bz * 1024 + j * 256 + tid;
            if (u < 697024) {
                int4 z = {0, 0, 0, 0};
                ((int4*)Xp)[u] = z;
            }
        }
    }
}

// ---------------------------------------------------------------------------
// Pack x -> Xp interior (bf16 packed-8, 66x66 padded planes). Halo was
// zeroed by k_prep; interior/halo are disjoint so no ordering hazard.
__global__ __launch_bounds__(256) void k_pack(const float* __restrict__ x,
                                              unsigned short* __restrict__ Xp)
{
    const int tid = threadIdx.x;
    const int sp = blockIdx.x, gl = blockIdx.y, b = blockIdx.z;
    const float* xb = x + ((size_t)b * 320 + gl * 8) * 4096;
    unsigned short* xpb = Xp + (size_t)(gl * 4 + b) * 4356 * 8;
    #pragma unroll
    for (int i = 0; i < 4; ++i) {
        int px = sp * 1024 + i * 256 + tid;
        float v0 = xb[0 * 4096 + px], v1 = xb[1 * 4096 + px];
        float v2 = xb[2 * 4096 + px], v3 = xb[3 * 4096 + px];
        float v4 = xb[4 * 4096 + px], v5 = xb[5 * 4096 + px];
        float v6 = xb[6 * 4096 + px], v7 = xb[7 * 4096 + px];
        int4 st;
        st.x = (int)pack2(v0, v1);
        st.y = (int)pack2(v2, v3);
        st.z = (int)pack2(v4, v5);
        st.w = (int)pack2(v6, v7);
        *(int4*)(xpb + (((px >> 6) + 1) * 66 + (px & 63) + 1) * 8) = st;
    }
}

// ---------------------------------------------------------------------------
// MFMA GEMM with fused im2col gather (round 6). r2 skeleton: BM=160, BN=128,
// BK=64, 4 waves 2Mx2N, per-wave 80x64, acc 5x4, dbuf LDS 72 KB, grid 512 =
// 2 blk/CU, one vmcnt-drain + barrier per K-step.
// dconv half: B-tile gathered from Xp (4 taps via oU base) + blended in-reg,
// ds_write to Bs. Taps issued BEFORE the MFMA cluster, blended AFTER (T14).
__global__ __launch_bounds__(256, 2) void k_gemm(const unsigned short* __restrict__ Xp,
                                                 const int* __restrict__ hoffG,
                                                 const unsigned short* __restrict__ Wr,
                                                 const uint32_t* __restrict__ oU,
                                                 const float* __restrict__ oWt,
                                                 unsigned short* __restrict__ Cc,
                                                 const float* __restrict__ bias)
{
    __shared__ __align__(16) unsigned short As[2][8 * 160 * 8];   // 2 x 20 KB
    __shared__ __align__(16) unsigned short Bs[2][8 * 128 * 8];   // 2 x 16 KB
    const int tid = threadIdx.x;
    const int n0 = blockIdx.x * 128, m0 = blockIdx.y * 160;
    const int lane = tid & 63, w = tid >> 6;
    const int wm = w & 1, wn = w >> 1;
    const int quad = lane >> 4, nl = lane & 15;
    const bool hHalf = (n0 >= 16384);
    int xbase;
    {
        int nnh = (n0 - 16384) + (tid & 127);
        int bh = nnh >> 12, pxh = nnh & 4095;
        xbase = (bh * 4356 + (pxh >> 6) * 66 + (pxh & 63)) * 8;
    }
    // dconv-half gather context (thread-constant; n-tile lies in one b).
    const int nn128 = n0 + (tid & 127);
    const int pimg  = nn128 & 4095;
    const int planeB = ((nn128 & 16383) >> 12) * 34848;   // b*4356*8
    const int row0  = tid >> 7;                            // rows row0+2q

#define STAGE_A(buf, s1) do { \
    _Pragma("unroll") \
    for (int q_ = 0; q_ < 5; ++q_) { \
        int u_ = tid + q_ * 256; \
        int kq_ = u_ / 160, m_ = u_ - kq_ * 160; \
        gl_lds16(Wr + ((size_t)(((s1) * 8 + kq_) * 384 + m0 + m_)) * 8, &As[buf][u_ * 8]); \
    } \
} while (0)

#define STAGE_BH(buf, s1) do { \
    _Pragma("unroll") \
    for (int q_ = 0; q_ < 4; ++q_) { \
        int u_ = tid + q_ * 256; \
        int kkb_ = (s1) * 8 + (u_ >> 7); \
        int off_ = hoffG[__builtin_amdgcn_readfirstlane(kkb_)]; \
        gl_lds16(Xp + (size_t)(xbase + off_), &Bs[buf][u_ * 8]); \
    } \
} while (0)

#define LOAD_REC(s1, BO, WV) do { \
    _Pragma("unroll") \
    for (int q_ = 0; q_ < 4; ++q_) { \
        int kkb_ = (s1) * 8 + row0 + 2 * q_; \
        int g_ = kkb_ / 9; int k9_ = kkb_ - g_ * 9; \
        int gi_ = (k9_ << 12) + pimg; \
        BO[q_] = oU[gi_]; \
        WV[q_] = *(const float4*)&oWt[(size_t)gi_ * 4]; \
    } \
} while (0)

#define LOAD_TAPS(s1) do { \
    _Pragma("unroll") \
    for (int q_ = 0; q_ < 4; ++q_) { \
        int kkb_ = (s1) * 8 + row0 + 2 * q_; \
        int g_ = kkb_ / 9; \
        const unsigned short* pb_ = Xp + (size_t)g_ * 139392 + planeB + bo[q_]; \
        tp[q_][0] = *(const int4*)pb_; \
        tp[q_][1] = *(const int4*)(pb_ + 8); \
        tp[q_][2] = *(const int4*)(pb_ + 528); \
        tp[q_][3] = *(const int4*)(pb_ + 536); \
    } \
} while (0)

#define BLEND_WRITE(buf) do { \
    _Pragma("unroll") \
    for (int q_ = 0; q_ < 4; ++q_) { \
        float ac[8]; \
        _Pragma("unroll") \
        for (int z_ = 0; z_ < 8; ++z_) ac[z_] = 0.f; \
        TAP(tp[q_][0], wv[q_].x) TAP(tp[q_][1], wv[q_].y) \
        TAP(tp[q_][2], wv[q_].z) TAP(tp[q_][3], wv[q_].w) \
        int4 st_; \
        st_.x = (int)pack2(ac[0], ac[1]); \
        st_.y = (int)pack2(ac[2], ac[3]); \
        st_.z = (int)pack2(ac[4], ac[5]); \
        st_.w = (int)pack2(ac[6], ac[7]); \
        *(int4*)&Bs[buf][(tid + q_ * 256) * 8] = st_; \
    } \
} while (0)

    uint32_t bo[4], nbo[4];
    float4 wv[4], nwv[4];
    int4 tp[4][4];

    f32x4 acc[5][4];
    #pragma unroll
    for (int mt = 0; mt < 5; ++mt)
        #pragma unroll
        for (int nt = 0; nt < 4; ++nt)
            acc[mt][nt] = 0.f;

    // Prologue: build tile 0, preload recs for tile 1.
    STAGE_A(0, 0);
    if (hHalf) {
        STAGE_BH(0, 0);
    } else {
        LOAD_REC(0, bo, wv);
        LOAD_TAPS(0);
        BLEND_WRITE(0);
        LOAD_REC(1, bo, wv);
    }
    asm volatile("s_waitcnt vmcnt(0) lgkmcnt(0)" ::: "memory");
    __builtin_amdgcn_s_barrier();
    __builtin_amdgcn_sched_barrier(0);

    for (int s = 0; s < 45; ++s) {
        const int p = s & 1, np = p ^ 1;
        if (s < 44) {
            STAGE_A(np, s + 1);
            if (hHalf) {
                STAGE_BH(np, s + 1);
            } else {
                LOAD_TAPS(s + 1);                 // issue-early (T14)
                if (s < 43) LOAD_REC(s + 2, nbo, nwv);
            }
        }
        __builtin_amdgcn_sched_barrier(0);
        #pragma unroll
        for (int kc = 0; kc < 2; ++kc) {
            bf16x8 a[5], bf[4];
            #pragma unroll
            for (int mt = 0; mt < 5; ++mt)
                a[mt] = *(const bf16x8*)&As[p][((kc * 4 + quad) * 160 + wm * 80 + mt * 16 + nl) * 8];
            #pragma unroll
            for (int nt = 0; nt < 4; ++nt)
                bf[nt] = *(const bf16x8*)&Bs[p][((kc * 4 + quad) * 128 + wn * 64 + nt * 16 + nl) * 8];
            #pragma unroll
            for (int mt = 0; mt < 5; ++mt)
                #pragma unroll
                for (int nt = 0; nt < 4; ++nt)
                    acc[mt][nt] = __builtin_amdgcn_mfma_f32_16x16x32_bf16(a[mt], bf[nt], acc[mt][nt], 0, 0, 0);
        }
        __builtin_amdgcn_sched_barrier(0);
        if (s < 44 && !hHalf) {
            BLEND_WRITE(np);                      // write-late (T14)
            if (s < 43) {
                #pragma unroll
                for (int q_ = 0; q_ < 4; ++q_) { bo[q_] = nbo[q_]; wv[q_] = nwv[q_]; }
            }
        }
        asm volatile("s_waitcnt vmcnt(0) lgkmcnt(0)" ::: "memory");
        __builtin_amdgcn_s_barrier();
        __builtin_amdgcn_sched_barrier(0);
    }

    // Epilogue: bias + pack to Cc. o0 = m0 + wm*80 + mt*16 + quad*4 < 320.
    #pragma unroll
    for (int mt = 0; mt < 5; ++mt) {
        int o0 = m0 + wm * 80 + mt * 16 + quad * 4;
        float bv0 = bias[o0 + 0];
        float bv1 = bias[o0 + 1];
        float bv2 = bias[o0 + 2];
        float bv3 = bias[o0 + 3];
        #pragma unroll
        for (int nt = 0; nt < 4; ++nt) {
            int n2 = n0 + wn * 64 + nt * 16 + nl;
            unsigned short* pp = Cc + ((size_t)(o0 >> 3) * 32768 + n2) * 8 + (o0 & 7);
            ushort4 st;
            st.x = f2b(acc[mt][nt][0] + bv0);
            st.y = f2b(acc[mt][nt][1] + bv1);
            st.z = f2b(acc[mt][nt][2] + bv2);
            st.w = f2b(acc[mt][nt][3] + bv3);
            *(ushort4*)pp = st;
        }
    }
#undef STAGE_A
#undef STAGE_BH
#undef LOAD_REC
#undef LOAD_TAPS
#undef BLEND_WRITE
}

// ---------------------------------------------------------------------------
// Final: out = h + scale * (W2 x [dconv; h]), K=640 as 10 BK=64 steps.
// BM=160 geometry (grid 128x2, per-wave 80x64) -> zero M-pad, no idle waves.
__global__ __launch_bounds__(256) void k_final(const unsigned short* __restrict__ W2,
                                               const unsigned short* __restrict__ Cc,
                                               const float* __restrict__ scale,
                                               float* __restrict__ out)
{
    __shared__ __align__(16) unsigned short As[8 * 160 * 8];   // 20 KB
    __shared__ __align__(16) unsigned short Bs[8 * 128 * 8];   // 16 KB
    const int tid = threadIdx.x;
    const int n0 = blockIdx.x * 128, m0 = blockIdx.y * 160;
    const int lane = tid & 63, w = tid >> 6;
    const int wm = w & 1, wn = w >> 1;
    const int quad = lane >> 4, nl = lane & 15;
    f32x4 acc[5][4];
    #pragma unroll
    for (int mt = 0; mt < 5; ++mt)
        #pragma unroll
        for (int nt = 0; nt < 4; ++nt)
            acc[mt][nt] = 0.f;

    for (int s = 0; s < 10; ++s) {
        __syncthreads();
        #pragma unroll
        for (int q = 0; q < 5; ++q) {
            int u = tid + q * 256;
            int kq = u / 160, m = u - kq * 160;
            gl_lds16(W2 + ((size_t)(s * 8 + kq) * 384 + m0 + m) * 8, &As[u * 8]);
        }
        int h_off = (s < 5) ? 0 : 16384;
        int gq = (s < 5) ? s * 8 : (s - 5) * 8;
        #pragma unroll
        for (int q = 0; q < 4; ++q) {
            int u = tid + q * 256;
            int row = u >> 7, nn = n0 + (u & 127);
            gl_lds16(Cc + ((size_t)(gq + row) * 32768 + h_off + nn) * 8, &Bs[u * 8]);
        }
        __syncthreads();
        #pragma unroll
        for (int kc = 0; kc < 2; ++kc) {
            bf16x8 a[5], bf[4];
            #pragma unroll
            for (int mt = 0; mt < 5; ++mt)
                a[mt] = *(const bf16x8*)&As[((kc * 4 + quad) * 160 + wm * 80 + mt * 16 + nl) * 8];
            #pragma unroll
            for (int nt = 0; nt < 4; ++nt)
                bf[nt] = *(const bf16x8*)&Bs[((kc * 4 + quad) * 128 + wn * 64 + nt * 16 + nl) * 8];
            #pragma unroll
            for (int mt = 0; mt < 5; ++mt)
                #pragma unroll
                for (int nt = 0; nt < 4; ++nt)
                    acc[mt][nt] = __builtin_amdgcn_mfma_f32_16x16x32_bf16(a[mt], bf[nt], acc[mt][nt], 0, 0, 0);
        }
    }

    float sc = scale[0];
    #pragma unroll
    for (int mt = 0; mt < 5; ++mt) {
        int o0 = m0 + wm * 80 + mt * 16 + quad * 4;
        #pragma unroll
        for (int nt = 0; nt < 4; ++nt) {
            int n = n0 + wn * 64 + nt * 16 + nl;
            int b = n >> 12, px = n & 4095;
            ushort4 hv = *(const ushort4*)(Cc + ((size_t)(o0 >> 3) * 32768 + n + 16384) * 8 + (o0 & 7));
            size_t base = ((size_t)(b * 320 + o0)) * 4096 + px;
            out[base]            = b2f(hv.x) + sc * acc[mt][nt][0];
            out[base + 4096]     = b2f(hv.y) + sc * acc[mt][nt][1];
            out[base + 2 * 4096] = b2f(hv.z) + sc * acc[mt][nt][2];
            out[base + 3 * 4096] = b2f(hv.w) + sc * acc[mt][nt][3];
        }
    }
}

// ---------------------------------------------------------------------------
extern "C" void kernel_launch(void* const* d_in, const int* in_sizes, int n_in,
                              void* d_out, int out_size, void* d_ws, size_t ws_size,
                              hipStream_t stream)
{
    const float* x      = (const float*)d_in[0];
    const float* weight = (const float*)d_in[1];
    const float* bias   = (const float*)d_in[2];
    const float* w_down = (const float*)d_in[3];
    const float* w_up   = (const float*)d_in[4];
    const float* scale  = (const float*)d_in[5];
    const float* offset = (const float*)d_in[6];
    char* ws = (char*)d_ws;
    unsigned short* Cc    = (unsigned short*)(ws + 0);
    unsigned short* Wr    = (unsigned short*)(ws + 25165824);
    unsigned short* W2    = (unsigned short*)(ws + 27377664);
    uint32_t*       oU    = (uint32_t*)(ws + 27869184);
    float*          oWt   = (float*)(ws + 28164096);
    int*            hoffG = (int*)(ws + 28753920);
    unsigned short* Xp    = (unsigned short*)(ws + 28758016);
    float* out = (float*)d_out;

    hipLaunchKernelGGL(k_prep, dim3(2327), dim3(256), 0, stream,
                       offset, weight, w_down, w_up, oU, oWt, Wr, W2, hoffG, Xp);
    hipLaunchKernelGGL(k_pack, dim3(4, 40, 4), dim3(256), 0, stream,
                       x, Xp);
    hipLaunchKernelGGL(k_gemm, dim3(256, 2), dim3(256), 0, stream,
                       Xp, hoffG, Wr, oU, oWt, Cc, bias);
    hipLaunchKernelGGL(k_final, dim3(128, 2), dim3(256), 0, stream,
                       W2, Cc, scale, out);
}

// Round 7
// 194.888 us; speedup vs baseline: 2.2626x; 2.2626x over previous
//
#include <hip/hip_runtime.h>
#include <stdint.h>

// B=4, C=O=320, H=W=64 -> HW=4096, N=16384 (b*4096+px), N2=32768 for Cc.
// Round 7: bilinear commuted past the channel contraction.
//   Z[(k,o), n] = sum_c w[o,c,k] x[c,n]   (GEMM: M=2880, N=16384, K=320)
//   dconv[o,p]  = sum_k sum_t wt_t(k,p) Z_k[o, idx_t(k,p)]      (k_blend)
//   h[o,p]      = sum_k Z_k[o, shift_k(p)] (conv3x3 = free from Z)
// GEMM FLOPs halved vs round 5 (no h-half GEMM); k_gather + Sd deleted.
//
// Layouts:
//   Wr2 packed-8 K-major: elem(m,c) at ((c>>3)*2880 + m)*8 + (c&7), m=k*320+o.
//   Xb  packed-8:         elem(c,n) at ((c>>3)*16384 + n)*8 + (c&7).
//   Z   packed-8:         elem(m,n) at ((m>>3)*16384 + n)*8 + (m&7).
//   Cc  packed-8:         elem(o,n2) at (o>>3)*32768*8 + n2*8 + (o&7);
//                         n2<16384 dconv+bias, n2>=16384 h+bias.
//   oIdx: 2 u32 per (k,p): (ya*64+xa)|(ya*64+xb)<<16 ; (yb*64+xa)|(yb*64+xb)<<16
//   oW:   float4 weights (OOB-validity folded in; indices clamped in-range).
//
// ws layout (bytes):
//   Cc 0..25,165,824 | Wr2 ..27,377,664 | W2 ..27,869,184 | oIdx ..28,164,096
//   oWt ..28,753,920 | Xb @28,758,016 | Z @39,909,376 (+94,371,840)

typedef __attribute__((ext_vector_type(4))) float f32x4;
typedef __attribute__((ext_vector_type(8))) short bf16x8;

typedef __attribute__((address_space(1))) const unsigned int uint_as1;
typedef __attribute__((address_space(3))) unsigned int uint_as3;

__device__ __forceinline__ void gl_lds16(const void* g, void* l) {
    __builtin_amdgcn_global_load_lds((uint_as1*)g, (uint_as3*)l, 16, 0, 0);
}

__device__ __forceinline__ unsigned short f2b(float f) {
    union { float f; uint32_t u; } v; v.f = f;
    uint32_t r = (v.u + 0x7FFFu + ((v.u >> 16) & 1u)) >> 16;
    return (unsigned short)r;
}
__device__ __forceinline__ float b2f(unsigned short h) {
    union { uint32_t u; float f; } v; v.u = ((uint32_t)h) << 16;
    return v.f;
}
__device__ __forceinline__ float b2f_lo(uint32_t u) {
    union { uint32_t u; float f; } v; v.u = u << 16;
    return v.f;
}
__device__ __forceinline__ float b2f_hi(uint32_t u) {
    union { uint32_t u; float f; } v; v.u = u & 0xFFFF0000u;
    return v.f;
}
__device__ __forceinline__ uint32_t pack2(float lo, float hi) {
    return (uint32_t)f2b(lo) | ((uint32_t)f2b(hi) << 16);
}

#define TAP8(AC, tv, wvx) \
    AC[0] += wvx * b2f_lo((uint32_t)tv.x); AC[1] += wvx * b2f_hi((uint32_t)tv.x); \
    AC[2] += wvx * b2f_lo((uint32_t)tv.y); AC[3] += wvx * b2f_hi((uint32_t)tv.y); \
    AC[4] += wvx * b2f_lo((uint32_t)tv.z); AC[5] += wvx * b2f_hi((uint32_t)tv.z); \
    AC[6] += wvx * b2f_lo((uint32_t)tv.w); AC[7] += wvx * b2f_hi((uint32_t)tv.w);

// ---------------------------------------------------------------------------
// Fused prep. [0,144) bilinear recs (oIdx pair + oW weights, r0-verified);
// [144,594) Wr2 (ushort8 coalesced); [594,1554) W2.
__global__ __launch_bounds__(256) void k_prep(const float* __restrict__ off,
                                              const float* __restrict__ w,
                                              const float* __restrict__ wd,
                                              const float* __restrict__ wu,
                                              uint32_t* __restrict__ oIdx,
                                              float* __restrict__ oW,
                                              unsigned short* __restrict__ Wr2,
                                              unsigned short* __restrict__ W2)
{
    const int bx = blockIdx.x, tid = threadIdx.x;
    if (bx < 144) {
        int gid = bx * 256 + tid;                    // 9*4096 exact
        int k = gid >> 12;
        int p = gid & 4095;
        int i = p >> 6, j = p & 63;
        float dy = off[(2 * k) * 4096 + p];
        float dx = off[(2 * k + 1) * 4096 + p];
        float py = (float)(i - 1 + k / 3) + dy;
        float px = (float)(j - 1 + k % 3) + dx;
        float fy = floorf(py), fx = floorf(px);
        float wy = py - fy, wx = px - fx;
        fy = fminf(fmaxf(fy, -100.f), 100.f);
        fx = fminf(fmaxf(fx, -100.f), 100.f);
        int y0 = (int)fy, x0 = (int)fx;
        float vy0 = (y0 >= 0 && y0 < 64) ? 1.f : 0.f;
        float vy1 = (y0 >= -1 && y0 < 63) ? 1.f : 0.f;
        float vx0 = (x0 >= 0 && x0 < 64) ? 1.f : 0.f;
        float vx1 = (x0 >= -1 && x0 < 63) ? 1.f : 0.f;
        float w00 = (1.f - wy) * (1.f - wx) * vy0 * vx0;
        float w01 = (1.f - wy) * wx * vy0 * vx1;
        float w10 = wy * (1.f - wx) * vy1 * vx0;
        float w11 = wy * wx * vy1 * vx1;
        int ya = min(max(y0, 0), 63), yb = min(max(y0 + 1, 0), 63);
        int xa = min(max(x0, 0), 63), xb = min(max(x0 + 1, 0), 63);
        oIdx[gid * 2 + 0] = (uint32_t)(ya * 64 + xa) | ((uint32_t)(ya * 64 + xb) << 16);
        oIdx[gid * 2 + 1] = (uint32_t)(yb * 64 + xa) | ((uint32_t)(yb * 64 + xb) << 16);
        oW[gid * 4 + 0] = w00;
        oW[gid * 4 + 1] = w01;
        oW[gid * 4 + 2] = w10;
        oW[gid * 4 + 3] = w11;
    } else if (bx < 594) {
        // Wr2: one thread per (cb, m); m = k*320+o; coalesced ushort8 store.
        // 450*256 = 115200 = 40*2880 exact.
        int gid = (bx - 144) * 256 + tid;
        int cb = gid / 2880, m = gid - cb * 2880;
        int k = m / 320, o = m - k * 320;
        float v[8];
        #pragma unroll
        for (int cl = 0; cl < 8; ++cl) {
            int c = cb * 8 + cl;
            v[cl] = w[((size_t)o * 320 + c) * 9 + k];
        }
        int4 st;
        st.x = (int)pack2(v[0], v[1]);
        st.y = (int)pack2(v[2], v[3]);
        st.z = (int)pack2(v[4], v[5]);
        st.w = (int)pack2(v[6], v[7]);
        *(int4*)(Wr2 + (size_t)gid * 8) = st;
    } else {
        int gid = (bx - 594) * 256 + tid;            // 384*640 exact
        int o = gid / 640, kk2 = gid % 640;
        float acc = 0.f;
        if (o < 320) {
            for (int l = 0; l < 320; ++l)
                acc += wu[o * 320 + l] * wd[l * 640 + kk2];
        }
        W2[(size_t)((kk2 >> 3) * 384 + o) * 8 + (kk2 & 7)] = f2b(acc);
    }
}

// ---------------------------------------------------------------------------
// Pack x -> Xb (bf16 packed-8, no padding): elem(c,n) at ((c>>3)*16384+n)*8+(c&7).
__global__ __launch_bounds__(256) void k_pack(const float* __restrict__ x,
                                              unsigned short* __restrict__ Xb)
{
    const int tid = threadIdx.x;
    const int sp = blockIdx.x, gl = blockIdx.y, b = blockIdx.z;
    const float* xb = x + ((size_t)b * 320 + gl * 8) * 4096;
    unsigned short* xpb = Xb + ((size_t)gl * 16384 + b * 4096) * 8;
    #pragma unroll
    for (int i = 0; i < 4; ++i) {
        int px = sp * 1024 + i * 256 + tid;
        float v0 = xb[0 * 4096 + px], v1 = xb[1 * 4096 + px];
        float v2 = xb[2 * 4096 + px], v3 = xb[3 * 4096 + px];
        float v4 = xb[4 * 4096 + px], v5 = xb[5 * 4096 + px];
        float v6 = xb[6 * 4096 + px], v7 = xb[7 * 4096 + px];
        int4 st;
        st.x = (int)pack2(v0, v1);
        st.y = (int)pack2(v2, v3);
        st.z = (int)pack2(v4, v5);
        st.w = (int)pack2(v6, v7);
        *(int4*)(xpb + (size_t)px * 8) = st;
    }
}

// ---------------------------------------------------------------------------
// Z-GEMM (r2-verified skeleton): M=2880 (18x160, zero pad), N=16384, K=320
// as 5 BK=64 steps. BM=160, BN=128, 4 waves 2Mx2N, per-wave 80x64, acc 5x4,
// dbuf LDS 72 KB, one vmcnt(0)+barrier per K-step. Z epilogue (no bias).
__global__ __launch_bounds__(256) void k_zgemm(const unsigned short* __restrict__ Xb,
                                               const unsigned short* __restrict__ Wr2,
                                               unsigned short* __restrict__ Z)
{
    __shared__ __align__(16) unsigned short As[2][8 * 160 * 8];   // 2 x 20 KB
    __shared__ __align__(16) unsigned short Bs[2][8 * 128 * 8];   // 2 x 16 KB
    const int tid = threadIdx.x;
    const int n0 = blockIdx.x * 128, m0 = blockIdx.y * 160;
    const int lane = tid & 63, w = tid >> 6;
    const int wm = w & 1, wn = w >> 1;
    const int quad = lane >> 4, nl = lane & 15;

#define STAGE(buf, s1) do { \
    _Pragma("unroll") \
    for (int q_ = 0; q_ < 5; ++q_) { \
        int u_ = tid + q_ * 256; \
        int kq_ = u_ / 160, m_ = u_ - kq_ * 160; \
        gl_lds16(Wr2 + ((size_t)(((s1) * 8 + kq_) * 2880 + m0 + m_)) * 8, &As[buf][u_ * 8]); \
    } \
    _Pragma("unroll") \
    for (int q_ = 0; q_ < 4; ++q_) { \
        int u_ = tid + q_ * 256; \
        int row_ = u_ >> 7, nn_ = n0 + (u_ & 127); \
        gl_lds16(Xb + ((size_t)((s1) * 8 + row_) * 16384 + nn_) * 8, &Bs[buf][u_ * 8]); \
    } \
} while (0)

    f32x4 acc[5][4];
    #pragma unroll
    for (int mt = 0; mt < 5; ++mt)
        #pragma unroll
        for (int nt = 0; nt < 4; ++nt)
            acc[mt][nt] = 0.f;

    STAGE(0, 0);
    asm volatile("s_waitcnt vmcnt(0)" ::: "memory");
    __builtin_amdgcn_s_barrier();
    __builtin_amdgcn_sched_barrier(0);

    for (int s = 0; s < 5; ++s) {
        const int p = s & 1, np = p ^ 1;
        if (s < 4) STAGE(np, s + 1);
        __builtin_amdgcn_sched_barrier(0);
        #pragma unroll
        for (int kc = 0; kc < 2; ++kc) {
            bf16x8 a[5], bf[4];
            #pragma unroll
            for (int mt = 0; mt < 5; ++mt)
                a[mt] = *(const bf16x8*)&As[p][((kc * 4 + quad) * 160 + wm * 80 + mt * 16 + nl) * 8];
            #pragma unroll
            for (int nt = 0; nt < 4; ++nt)
                bf[nt] = *(const bf16x8*)&Bs[p][((kc * 4 + quad) * 128 + wn * 64 + nt * 16 + nl) * 8];
            #pragma unroll
            for (int mt = 0; mt < 5; ++mt)
                #pragma unroll
                for (int nt = 0; nt < 4; ++nt)
                    acc[mt][nt] = __builtin_amdgcn_mfma_f32_16x16x32_bf16(a[mt], bf[nt], acc[mt][nt], 0, 0, 0);
        }
        asm volatile("s_waitcnt vmcnt(0)" ::: "memory");
        __builtin_amdgcn_s_barrier();
        __builtin_amdgcn_sched_barrier(0);
    }

    // Epilogue: pack to Z (no bias). m index in [0,2880).
    #pragma unroll
    for (int mt = 0; mt < 5; ++mt) {
        int o0m = m0 + wm * 80 + mt * 16 + quad * 4;
        #pragma unroll
        for (int nt = 0; nt < 4; ++nt) {
            int n2 = n0 + wn * 64 + nt * 16 + nl;
            unsigned short* pp = Z + ((size_t)(o0m >> 3) * 16384 + n2) * 8 + (o0m & 7);
            ushort4 st;
            st.x = f2b(acc[mt][nt][0]);
            st.y = f2b(acc[mt][nt][1]);
            st.z = f2b(acc[mt][nt][2]);
            st.w = f2b(acc[mt][nt][3]);
            *(ushort4*)pp = st;
        }
    }
#undef STAGE
}

// ---------------------------------------------------------------------------
// Blend: Cc dconv-half = sum_k 4-tap bilinear of Z_k (+bias);
//        Cc h-half     = sum_k shifted Z_k (conv3x3, zero-pad) (+bias).
// grid (16 px-splits, 10 og-groups, 4 b); thread = one px; loops 4 og.
__global__ __launch_bounds__(256) void k_blend(const unsigned short* __restrict__ Z,
                                               const uint32_t* __restrict__ oIdx,
                                               const float* __restrict__ oW,
                                               const float* __restrict__ bias,
                                               unsigned short* __restrict__ Cc)
{
    const int tid = threadIdx.x;
    const int px = blockIdx.x * 256 + tid;
    const int og0 = blockIdx.y * 4;
    const int b = blockIdx.z;
    const int r = px >> 6, c0 = px & 63;

    // Per-k records (k unrolled -> static register indexing).
    uint32_t i0[9], i1[9];
    float4 wv[9];
    int hidx[9];
    float hw[9];
    #pragma unroll
    for (int k = 0; k < 9; ++k) {
        int gi = (k << 12) + px;
        i0[k] = oIdx[gi * 2];
        i1[k] = oIdx[gi * 2 + 1];
        wv[k] = *(const float4*)&oW[(size_t)gi * 4];
        int rr = r + k / 3 - 1, cc = c0 + k % 3 - 1;
        bool valid = (rr >= 0) & (rr < 64) & (cc >= 0) & (cc < 64);
        hidx[k] = valid ? (rr * 64 + cc) : 0;
        hw[k] = valid ? 1.f : 0.f;
    }

    for (int oi = 0; oi < 4; ++oi) {
        int og = og0 + oi;
        float ac[8], ah[8];
        {
            float4 b0 = *(const float4*)&bias[og * 8];
            float4 b1 = *(const float4*)&bias[og * 8 + 4];
            ac[0] = b0.x; ac[1] = b0.y; ac[2] = b0.z; ac[3] = b0.w;
            ac[4] = b1.x; ac[5] = b1.y; ac[6] = b1.z; ac[7] = b1.w;
            #pragma unroll
            for (int j = 0; j < 8; ++j) ah[j] = ac[j];
        }
        #pragma unroll
        for (int k = 0; k < 9; ++k) {
            const unsigned short* Zb = Z + ((size_t)(k * 40 + og) * 16384 + b * 4096) * 8;
            int4 t0 = *(const int4*)(Zb + (size_t)(i0[k] & 0xFFFFu) * 8);
            int4 t1 = *(const int4*)(Zb + (size_t)(i0[k] >> 16) * 8);
            int4 t2 = *(const int4*)(Zb + (size_t)(i1[k] & 0xFFFFu) * 8);
            int4 t3 = *(const int4*)(Zb + (size_t)(i1[k] >> 16) * 8);
            int4 th = *(const int4*)(Zb + (size_t)hidx[k] * 8);
            TAP8(ac, t0, wv[k].x) TAP8(ac, t1, wv[k].y)
            TAP8(ac, t2, wv[k].z) TAP8(ac, t3, wv[k].w)
            TAP8(ah, th, hw[k])
        }
        int4 sd, sh;
        sd.x = (int)pack2(ac[0], ac[1]); sd.y = (int)pack2(ac[2], ac[3]);
        sd.z = (int)pack2(ac[4], ac[5]); sd.w = (int)pack2(ac[6], ac[7]);
        sh.x = (int)pack2(ah[0], ah[1]); sh.y = (int)pack2(ah[2], ah[3]);
        sh.z = (int)pack2(ah[4], ah[5]); sh.w = (int)pack2(ah[6], ah[7]);
        unsigned short* cp = Cc + ((size_t)og * 32768 + b * 4096 + px) * 8;
        *(int4*)cp = sd;
        *(int4*)(cp + 16384 * 8) = sh;
    }
}

// ---------------------------------------------------------------------------
// Final: out = h + scale * (W2 x [dconv; h]), K=640 as 10 BK=64 steps.
// BM=160 geometry (grid 128x2, per-wave 80x64) -> zero M-pad, no idle waves.
__global__ __launch_bounds__(256) void k_final(const unsigned short* __restrict__ W2,
                                               const unsigned short* __restrict__ Cc,
                                               const float* __restrict__ scale,
                                               float* __restrict__ out)
{
    __shared__ __align__(16) unsigned short As[8 * 160 * 8];   // 20 KB
    __shared__ __align__(16) unsigned short Bs[8 * 128 * 8];   // 16 KB
    const int tid = threadIdx.x;
    const int n0 = blockIdx.x * 128, m0 = blockIdx.y * 160;
    const int lane = tid & 63, w = tid >> 6;
    const int wm = w & 1, wn = w >> 1;
    const int quad = lane >> 4, nl = lane & 15;
    f32x4 acc[5][4];
    #pragma unroll
    for (int mt = 0; mt < 5; ++mt)
        #pragma unroll
        for (int nt = 0; nt < 4; ++nt)
            acc[mt][nt] = 0.f;

    for (int s = 0; s < 10; ++s) {
        __syncthreads();
        #pragma unroll
        for (int q = 0; q < 5; ++q) {
            int u = tid + q * 256;
            int kq = u / 160, m = u - kq * 160;
            gl_lds16(W2 + ((size_t)(s * 8 + kq) * 384 + m0 + m) * 8, &As[u * 8]);
        }
        int h_off = (s < 5) ? 0 : 16384;
        int gq = (s < 5) ? s * 8 : (s - 5) * 8;
        #pragma unroll
        for (int q = 0; q < 4; ++q) {
            int u = tid + q * 256;
            int row = u >> 7, nn = n0 + (u & 127);
            gl_lds16(Cc + ((size_t)(gq + row) * 32768 + h_off + nn) * 8, &Bs[u * 8]);
        }
        __syncthreads();
        #pragma unroll
        for (int kc = 0; kc < 2; ++kc) {
            bf16x8 a[5], bf[4];
            #pragma unroll
            for (int mt = 0; mt < 5; ++mt)
                a[mt] = *(const bf16x8*)&As[((kc * 4 + quad) * 160 + wm * 80 + mt * 16 + nl) * 8];
            #pragma unroll
            for (int nt = 0; nt < 4; ++nt)
                bf[nt] = *(const bf16x8*)&Bs[((kc * 4 + quad) * 128 + wn * 64 + nt * 16 + nl) * 8];
            #pragma unroll
            for (int mt = 0; mt < 5; ++mt)
                #pragma unroll
                for (int nt = 0; nt < 4; ++nt)
                    acc[mt][nt] = __builtin_amdgcn_mfma_f32_16x16x32_bf16(a[mt], bf[nt], acc[mt][nt], 0, 0, 0);
        }
    }

    float sc = scale[0];
    #pragma unroll
    for (int mt = 0; mt < 5; ++mt) {
        int o0 = m0 + wm * 80 + mt * 16 + quad * 4;
        #pragma unroll
        for (int nt = 0; nt < 4; ++nt) {
            int n = n0 + wn * 64 + nt * 16 + nl;
            int b = n >> 12, px = n & 4095;
            ushort4 hv = *(const ushort4*)(Cc + ((size_t)(o0 >> 3) * 32768 + n + 16384) * 8 + (o0 & 7));
            size_t base = ((size_t)(b * 320 + o0)) * 4096 + px;
            out[base]            = b2f(hv.x) + sc * acc[mt][nt][0];
            out[base + 4096]     = b2f(hv.y) + sc * acc[mt][nt][1];
            out[base + 2 * 4096] = b2f(hv.z) + sc * acc[mt][nt][2];
            out[base + 3 * 4096] = b2f(hv.w) + sc * acc[mt][nt][3];
        }
    }
}

// ---------------------------------------------------------------------------
extern "C" void kernel_launch(void* const* d_in, const int* in_sizes, int n_in,
                              void* d_out, int out_size, void* d_ws, size_t ws_size,
                              hipStream_t stream)
{
    const float* x      = (const float*)d_in[0];
    const float* weight = (const float*)d_in[1];
    const float* bias   = (const float*)d_in[2];
    const float* w_down = (const float*)d_in[3];
    const float* w_up   = (const float*)d_in[4];
    const float* scale  = (const float*)d_in[5];
    const float* offset = (const float*)d_in[6];
    char* ws = (char*)d_ws;
    unsigned short* Cc    = (unsigned short*)(ws + 0);
    unsigned short* Wr2   = (unsigned short*)(ws + 25165824);
    unsigned short* W2    = (unsigned short*)(ws + 27377664);
    uint32_t*       oI    = (uint32_t*)(ws + 27869184);
    float*          oWt   = (float*)(ws + 28164096);
    unsigned short* Xb    = (unsigned short*)(ws + 28758016);
    unsigned short* Z     = (unsigned short*)(ws + 39909376);
    float* out = (float*)d_out;

    hipLaunchKernelGGL(k_prep, dim3(1554), dim3(256), 0, stream,
                       offset, weight, w_down, w_up, oI, oWt, Wr2, W2);
    hipLaunchKernelGGL(k_pack, dim3(4, 40, 4), dim3(256), 0, stream,
                       x, Xb);
    hipLaunchKernelGGL(k_zgemm, dim3(128, 18), dim3(256), 0, stream,
                       Xb, Wr2, Z);
    hipLaunchKernelGGL(k_blend, dim3(16, 10, 4), dim3(256), 0, stream,
                       Z, oI, oWt, bias, Cc);
    hipLaunchKernelGGL(k_final, dim3(128, 2), dim3(256), 0, stream,
                       W2, Cc, scale, out);
}

// Round 9
// 189.404 us; speedup vs baseline: 2.3281x; 1.0290x over previous
//
#include <hip/hip_runtime.h>
#include <stdint.h>

// B=4, C=O=320, H=W=64 -> HW=4096, N=16384 (b*4096+px), N2=32768 for Cc.
// Round 9 = round 8 with the k_final launch-geometry fix (BN=64 -> 256
// n-blocks; r8 launched 512 -> OOB out-writes -> core dump).
//   Z[(k,o), n] = sum_c w[o,c,k] x[c,n]   (GEMM: M=2880, N=16384, K=320)
//   dconv[o,p]  = sum_k sum_t wt_t(k,p) Z_k[o, idx_t(k,p)]      (k_blend)
//   h[o,p]      = sum_k Z_k[o, shift_k(p)] (conv3x3 = free from Z)
// vs r7: k_pack merged into k_prep (one launch fewer, concurrent);
// W2 branch vectorized (float4 wu, 4 indep FMA chains); k_final upgraded to
// the r2-proven dbuf 2-phase schedule at BN=64 (56 KB LDS -> 2 blk/CU,
// grid 256x2 = 512 blocks = 2/CU exact). zgemm/blend unchanged (r7-verified).
//
// Layouts:
//   Wr2 packed-8 K-major: elem(m,c) at ((c>>3)*2880 + m)*8 + (c&7), m=k*320+o.
//   Xb  packed-8:         elem(c,n) at ((c>>3)*16384 + n)*8 + (c&7).
//   Z   packed-8:         elem(m,n) at ((m>>3)*16384 + n)*8 + (m&7).
//   Cc  packed-8:         elem(o,n2) at (o>>3)*32768*8 + n2*8 + (o&7);
//                         n2<16384 dconv+bias, n2>=16384 h+bias.
//   oIdx: 2 u32 per (k,p); oW: float4 weights (validity folded).
//
// ws layout (bytes):
//   Cc 0..25,165,824 | Wr2 ..27,377,664 | W2 ..27,869,184 | oIdx ..28,164,096
//   oWt ..28,753,920 | Xb @28,758,016 | Z @39,909,376 (+94,371,840)

typedef __attribute__((ext_vector_type(4))) float f32x4;
typedef __attribute__((ext_vector_type(8))) short bf16x8;

typedef __attribute__((address_space(1))) const unsigned int uint_as1;
typedef __attribute__((address_space(3))) unsigned int uint_as3;

__device__ __forceinline__ void gl_lds16(const void* g, void* l) {
    __builtin_amdgcn_global_load_lds((uint_as1*)g, (uint_as3*)l, 16, 0, 0);
}

__device__ __forceinline__ unsigned short f2b(float f) {
    union { float f; uint32_t u; } v; v.f = f;
    uint32_t r = (v.u + 0x7FFFu + ((v.u >> 16) & 1u)) >> 16;
    return (unsigned short)r;
}
__device__ __forceinline__ float b2f(unsigned short h) {
    union { uint32_t u; float f; } v; v.u = ((uint32_t)h) << 16;
    return v.f;
}
__device__ __forceinline__ float b2f_lo(uint32_t u) {
    union { uint32_t u; float f; } v; v.u = u << 16;
    return v.f;
}
__device__ __forceinline__ float b2f_hi(uint32_t u) {
    union { uint32_t u; float f; } v; v.u = u & 0xFFFF0000u;
    return v.f;
}
__device__ __forceinline__ uint32_t pack2(float lo, float hi) {
    return (uint32_t)f2b(lo) | ((uint32_t)f2b(hi) << 16);
}

#define TAP8(AC, tv, wvx) \
    AC[0] += wvx * b2f_lo((uint32_t)tv.x); AC[1] += wvx * b2f_hi((uint32_t)tv.x); \
    AC[2] += wvx * b2f_lo((uint32_t)tv.y); AC[3] += wvx * b2f_hi((uint32_t)tv.y); \
    AC[4] += wvx * b2f_lo((uint32_t)tv.z); AC[5] += wvx * b2f_hi((uint32_t)tv.z); \
    AC[6] += wvx * b2f_lo((uint32_t)tv.w); AC[7] += wvx * b2f_hi((uint32_t)tv.w);

// ---------------------------------------------------------------------------
// Fused prep. [0,144) bilinear recs; [144,594) Wr2 (ushort8 coalesced);
// [594,1554) W2 (float4-vectorized reduce); [1554,2194) x->Xb pack (merged
// k_pack; independent of the other branches, runs concurrently).
__global__ __launch_bounds__(256) void k_prep(const float* __restrict__ off,
                                              const float* __restrict__ w,
                                              const float* __restrict__ wd,
                                              const float* __restrict__ wu,
                                              const float* __restrict__ x,
                                              uint32_t* __restrict__ oIdx,
                                              float* __restrict__ oW,
                                              unsigned short* __restrict__ Wr2,
                                              unsigned short* __restrict__ W2,
                                              unsigned short* __restrict__ Xb)
{
    const int bx = blockIdx.x, tid = threadIdx.x;
    if (bx < 144) {
        int gid = bx * 256 + tid;                    // 9*4096 exact
        int k = gid >> 12;
        int p = gid & 4095;
        int i = p >> 6, j = p & 63;
        float dy = off[(2 * k) * 4096 + p];
        float dx = off[(2 * k + 1) * 4096 + p];
        float py = (float)(i - 1 + k / 3) + dy;
        float px = (float)(j - 1 + k % 3) + dx;
        float fy = floorf(py), fx = floorf(px);
        float wy = py - fy, wx = px - fx;
        fy = fminf(fmaxf(fy, -100.f), 100.f);
        fx = fminf(fmaxf(fx, -100.f), 100.f);
        int y0 = (int)fy, x0 = (int)fx;
        float vy0 = (y0 >= 0 && y0 < 64) ? 1.f : 0.f;
        float vy1 = (y0 >= -1 && y0 < 63) ? 1.f : 0.f;
        float vx0 = (x0 >= 0 && x0 < 64) ? 1.f : 0.f;
        float vx1 = (x0 >= -1 && x0 < 63) ? 1.f : 0.f;
        float w00 = (1.f - wy) * (1.f - wx) * vy0 * vx0;
        float w01 = (1.f - wy) * wx * vy0 * vx1;
        float w10 = wy * (1.f - wx) * vy1 * vx0;
        float w11 = wy * wx * vy1 * vx1;
        int ya = min(max(y0, 0), 63), yb = min(max(y0 + 1, 0), 63);
        int xa = min(max(x0, 0), 63), xb = min(max(x0 + 1, 0), 63);
        oIdx[gid * 2 + 0] = (uint32_t)(ya * 64 + xa) | ((uint32_t)(ya * 64 + xb) << 16);
        oIdx[gid * 2 + 1] = (uint32_t)(yb * 64 + xa) | ((uint32_t)(yb * 64 + xb) << 16);
        oW[gid * 4 + 0] = w00;
        oW[gid * 4 + 1] = w01;
        oW[gid * 4 + 2] = w10;
        oW[gid * 4 + 3] = w11;
    } else if (bx < 594) {
        // Wr2: one thread per (cb, m); m = k*320+o; coalesced ushort8 store.
        // 450*256 = 115200 = 40*2880 exact.
        int gid = (bx - 144) * 256 + tid;
        int cb = gid / 2880, m = gid - cb * 2880;
        int k = m / 320, o = m - k * 320;
        float v[8];
        #pragma unroll
        for (int cl = 0; cl < 8; ++cl) {
            int c = cb * 8 + cl;
            v[cl] = w[((size_t)o * 320 + c) * 9 + k];
        }
        int4 st;
        st.x = (int)pack2(v[0], v[1]);
        st.y = (int)pack2(v[2], v[3]);
        st.z = (int)pack2(v[4], v[5]);
        st.w = (int)pack2(v[6], v[7]);
        *(int4*)(Wr2 + (size_t)gid * 8) = st;
    } else if (bx < 1554) {
        // W2 = wu @ wd, float4-vectorized over l (4 independent chains).
        int gid = (bx - 594) * 256 + tid;            // 384*640 exact
        int o = gid / 640, kk2 = gid % 640;
        float a0 = 0.f, a1 = 0.f, a2 = 0.f, a3 = 0.f;
        if (o < 320) {
            const float* wuo = wu + (size_t)o * 320;
            for (int l = 0; l < 320; l += 4) {
                float4 u4 = *(const float4*)(wuo + l);
                a0 += u4.x * wd[(size_t)(l + 0) * 640 + kk2];
                a1 += u4.y * wd[(size_t)(l + 1) * 640 + kk2];
                a2 += u4.z * wd[(size_t)(l + 2) * 640 + kk2];
                a3 += u4.w * wd[(size_t)(l + 3) * 640 + kk2];
            }
        }
        W2[(size_t)((kk2 >> 3) * 384 + o) * 8 + (kk2 & 7)] = f2b((a0 + a1) + (a2 + a3));
    } else {
        // Pack x -> Xb (bf16 packed-8): elem(c,n) at ((c>>3)*16384+n)*8+(c&7).
        int bz = bx - 1554;                          // 640 blocks
        int sp = bz & 3, rest = bz >> 2;
        int gl = rest % 40, b = rest / 40;
        const float* xb = x + ((size_t)b * 320 + gl * 8) * 4096;
        unsigned short* xpb = Xb + ((size_t)gl * 16384 + b * 4096) * 8;
        #pragma unroll
        for (int i = 0; i < 4; ++i) {
            int px = sp * 1024 + i * 256 + tid;
            float v0 = xb[0 * 4096 + px], v1 = xb[1 * 4096 + px];
            float v2 = xb[2 * 4096 + px], v3 = xb[3 * 4096 + px];
            float v4 = xb[4 * 4096 + px], v5 = xb[5 * 4096 + px];
            float v6 = xb[6 * 4096 + px], v7 = xb[7 * 4096 + px];
            int4 st;
            st.x = (int)pack2(v0, v1);
            st.y = (int)pack2(v2, v3);
            st.z = (int)pack2(v4, v5);
            st.w = (int)pack2(v6, v7);
            *(int4*)(xpb + (size_t)px * 8) = st;
        }
    }
}

// ---------------------------------------------------------------------------
// Z-GEMM (r2-verified skeleton): M=2880 (18x160, zero pad), N=16384, K=320
// as 5 BK=64 steps. BM=160, BN=128, 4 waves 2Mx2N, per-wave 80x64, acc 5x4,
// dbuf LDS 72 KB, one vmcnt(0)+barrier per K-step. Z epilogue (no bias).
__global__ __launch_bounds__(256) void k_zgemm(const unsigned short* __restrict__ Xb,
                                               const unsigned short* __restrict__ Wr2,
                                               unsigned short* __restrict__ Z)
{
    __shared__ __align__(16) unsigned short As[2][8 * 160 * 8];   // 2 x 20 KB
    __shared__ __align__(16) unsigned short Bs[2][8 * 128 * 8];   // 2 x 16 KB
    const int tid = threadIdx.x;
    const int n0 = blockIdx.x * 128, m0 = blockIdx.y * 160;
    const int lane = tid & 63, w = tid >> 6;
    const int wm = w & 1, wn = w >> 1;
    const int quad = lane >> 4, nl = lane & 15;

#define STAGE(buf, s1) do { \
    _Pragma("unroll") \
    for (int q_ = 0; q_ < 5; ++q_) { \
        int u_ = tid + q_ * 256; \
        int kq_ = u_ / 160, m_ = u_ - kq_ * 160; \
        gl_lds16(Wr2 + ((size_t)(((s1) * 8 + kq_) * 2880 + m0 + m_)) * 8, &As[buf][u_ * 8]); \
    } \
    _Pragma("unroll") \
    for (int q_ = 0; q_ < 4; ++q_) { \
        int u_ = tid + q_ * 256; \
        int row_ = u_ >> 7, nn_ = n0 + (u_ & 127); \
        gl_lds16(Xb + ((size_t)((s1) * 8 + row_) * 16384 + nn_) * 8, &Bs[buf][u_ * 8]); \
    } \
} while (0)

    f32x4 acc[5][4];
    #pragma unroll
    for (int mt = 0; mt < 5; ++mt)
        #pragma unroll
        for (int nt = 0; nt < 4; ++nt)
            acc[mt][nt] = 0.f;

    STAGE(0, 0);
    asm volatile("s_waitcnt vmcnt(0)" ::: "memory");
    __builtin_amdgcn_s_barrier();
    __builtin_amdgcn_sched_barrier(0);

    for (int s = 0; s < 5; ++s) {
        const int p = s & 1, np = p ^ 1;
        if (s < 4) STAGE(np, s + 1);
        __builtin_amdgcn_sched_barrier(0);
        #pragma unroll
        for (int kc = 0; kc < 2; ++kc) {
            bf16x8 a[5], bf[4];
            #pragma unroll
            for (int mt = 0; mt < 5; ++mt)
                a[mt] = *(const bf16x8*)&As[p][((kc * 4 + quad) * 160 + wm * 80 + mt * 16 + nl) * 8];
            #pragma unroll
            for (int nt = 0; nt < 4; ++nt)
                bf[nt] = *(const bf16x8*)&Bs[p][((kc * 4 + quad) * 128 + wn * 64 + nt * 16 + nl) * 8];
            #pragma unroll
            for (int mt = 0; mt < 5; ++mt)
                #pragma unroll
                for (int nt = 0; nt < 4; ++nt)
                    acc[mt][nt] = __builtin_amdgcn_mfma_f32_16x16x32_bf16(a[mt], bf[nt], acc[mt][nt], 0, 0, 0);
        }
        asm volatile("s_waitcnt vmcnt(0)" ::: "memory");
        __builtin_amdgcn_s_barrier();
        __builtin_amdgcn_sched_barrier(0);
    }

    // Epilogue: pack to Z (no bias). m index in [0,2880).
    #pragma unroll
    for (int mt = 0; mt < 5; ++mt) {
        int o0m = m0 + wm * 80 + mt * 16 + quad * 4;
        #pragma unroll
        for (int nt = 0; nt < 4; ++nt) {
            int n2 = n0 + wn * 64 + nt * 16 + nl;
            unsigned short* pp = Z + ((size_t)(o0m >> 3) * 16384 + n2) * 8 + (o0m & 7);
            ushort4 st;
            st.x = f2b(acc[mt][nt][0]);
            st.y = f2b(acc[mt][nt][1]);
            st.z = f2b(acc[mt][nt][2]);
            st.w = f2b(acc[mt][nt][3]);
            *(ushort4*)pp = st;
        }
    }
#undef STAGE
}

// ---------------------------------------------------------------------------
// Blend: Cc dconv-half = sum_k 4-tap bilinear of Z_k (+bias);
//        Cc h-half     = sum_k shifted Z_k (conv3x3, zero-pad) (+bias).
// grid (16 px-splits, 10 og-groups, 4 b); thread = one px; loops 4 og.
__global__ __launch_bounds__(256) void k_blend(const unsigned short* __restrict__ Z,
                                               const uint32_t* __restrict__ oIdx,
                                               const float* __restrict__ oW,
                                               const float* __restrict__ bias,
                                               unsigned short* __restrict__ Cc)
{
    const int tid = threadIdx.x;
    const int px = blockIdx.x * 256 + tid;
    const int og0 = blockIdx.y * 4;
    const int b = blockIdx.z;
    const int r = px >> 6, c0 = px & 63;

    uint32_t i0[9], i1[9];
    float4 wv[9];
    int hidx[9];
    float hw[9];
    #pragma unroll
    for (int k = 0; k < 9; ++k) {
        int gi = (k << 12) + px;
        i0[k] = oIdx[gi * 2];
        i1[k] = oIdx[gi * 2 + 1];
        wv[k] = *(const float4*)&oW[(size_t)gi * 4];
        int rr = r + k / 3 - 1, cc = c0 + k % 3 - 1;
        bool valid = (rr >= 0) & (rr < 64) & (cc >= 0) & (cc < 64);
        hidx[k] = valid ? (rr * 64 + cc) : 0;
        hw[k] = valid ? 1.f : 0.f;
    }

    for (int oi = 0; oi < 4; ++oi) {
        int og = og0 + oi;
        float ac[8], ah[8];
        {
            float4 b0 = *(const float4*)&bias[og * 8];
            float4 b1 = *(const float4*)&bias[og * 8 + 4];
            ac[0] = b0.x; ac[1] = b0.y; ac[2] = b0.z; ac[3] = b0.w;
            ac[4] = b1.x; ac[5] = b1.y; ac[6] = b1.z; ac[7] = b1.w;
            #pragma unroll
            for (int j = 0; j < 8; ++j) ah[j] = ac[j];
        }
        #pragma unroll
        for (int k = 0; k < 9; ++k) {
            const unsigned short* Zb = Z + ((size_t)(k * 40 + og) * 16384 + b * 4096) * 8;
            int4 t0 = *(const int4*)(Zb + (size_t)(i0[k] & 0xFFFFu) * 8);
            int4 t1 = *(const int4*)(Zb + (size_t)(i0[k] >> 16) * 8);
            int4 t2 = *(const int4*)(Zb + (size_t)(i1[k] & 0xFFFFu) * 8);
            int4 t3 = *(const int4*)(Zb + (size_t)(i1[k] >> 16) * 8);
            int4 th = *(const int4*)(Zb + (size_t)hidx[k] * 8);
            TAP8(ac, t0, wv[k].x) TAP8(ac, t1, wv[k].y)
            TAP8(ac, t2, wv[k].z) TAP8(ac, t3, wv[k].w)
            TAP8(ah, th, hw[k])
        }
        int4 sd, sh;
        sd.x = (int)pack2(ac[0], ac[1]); sd.y = (int)pack2(ac[2], ac[3]);
        sd.z = (int)pack2(ac[4], ac[5]); sd.w = (int)pack2(ac[6], ac[7]);
        sh.x = (int)pack2(ah[0], ah[1]); sh.y = (int)pack2(ah[2], ah[3]);
        sh.z = (int)pack2(ah[4], ah[5]); sh.w = (int)pack2(ah[6], ah[7]);
        unsigned short* cp = Cc + ((size_t)og * 32768 + b * 4096 + px) * 8;
        *(int4*)cp = sd;
        *(int4*)(cp + 16384 * 8) = sh;
    }
}

// ---------------------------------------------------------------------------
// Final: out = h + scale * (W2 x [dconv; h]), K=640 as 10 BK=64 steps.
// r2-style dbuf 2-phase, BM=160 x BN=64, 4 waves 2Mx2N, per-wave 80x32,
// acc 5x2. LDS 2x20 + 2x8 = 56 KB -> 2 blk/CU; grid 256x2 = 512 = 2/CU.
__global__ __launch_bounds__(256) void k_final(const unsigned short* __restrict__ W2,
                                               const unsigned short* __restrict__ Cc,
                                               const float* __restrict__ scale,
                                               float* __restrict__ out)
{
    __shared__ __align__(16) unsigned short As[2][8 * 160 * 8];   // 2 x 20 KB
    __shared__ __align__(16) unsigned short Bs[2][8 * 64 * 8];    // 2 x 8 KB
    const int tid = threadIdx.x;
    const int n0 = blockIdx.x * 64, m0 = blockIdx.y * 160;
    const int lane = tid & 63, w = tid >> 6;
    const int wm = w & 1, wn = w >> 1;
    const int quad = lane >> 4, nl = lane & 15;

#define STAGEF(buf, s1) do { \
    _Pragma("unroll") \
    for (int q_ = 0; q_ < 5; ++q_) { \
        int u_ = tid + q_ * 256; \
        int kq_ = u_ / 160, m_ = u_ - kq_ * 160; \
        gl_lds16(W2 + ((size_t)(((s1) * 8 + kq_) * 384 + m0 + m_)) * 8, &As[buf][u_ * 8]); \
    } \
    { \
        int h_off_ = ((s1) < 5) ? 0 : 16384; \
        int gq_ = ((s1) < 5) ? (s1) * 8 : ((s1) - 5) * 8; \
        _Pragma("unroll") \
        for (int q_ = 0; q_ < 2; ++q_) { \
            int u_ = tid + q_ * 256; \
            int row_ = u_ >> 6, nn_ = n0 + (u_ & 63); \
            gl_lds16(Cc + ((size_t)(gq_ + row_) * 32768 + h_off_ + nn_) * 8, &Bs[buf][u_ * 8]); \
        } \
    } \
} while (0)

    f32x4 acc[5][2];
    #pragma unroll
    for (int mt = 0; mt < 5; ++mt)
        #pragma unroll
        for (int nt = 0; nt < 2; ++nt)
            acc[mt][nt] = 0.f;

    STAGEF(0, 0);
    asm volatile("s_waitcnt vmcnt(0)" ::: "memory");
    __builtin_amdgcn_s_barrier();
    __builtin_amdgcn_sched_barrier(0);

    for (int s = 0; s < 10; ++s) {
        const int p = s & 1, np = p ^ 1;
        if (s < 9) STAGEF(np, s + 1);
        __builtin_amdgcn_sched_barrier(0);
        #pragma unroll
        for (int kc = 0; kc < 2; ++kc) {
            bf16x8 a[5], bf[2];
            #pragma unroll
            for (int mt = 0; mt < 5; ++mt)
                a[mt] = *(const bf16x8*)&As[p][((kc * 4 + quad) * 160 + wm * 80 + mt * 16 + nl) * 8];
            #pragma unroll
            for (int nt = 0; nt < 2; ++nt)
                bf[nt] = *(const bf16x8*)&Bs[p][((kc * 4 + quad) * 64 + wn * 32 + nt * 16 + nl) * 8];
            #pragma unroll
            for (int mt = 0; mt < 5; ++mt)
                #pragma unroll
                for (int nt = 0; nt < 2; ++nt)
                    acc[mt][nt] = __builtin_amdgcn_mfma_f32_16x16x32_bf16(a[mt], bf[nt], acc[mt][nt], 0, 0, 0);
        }
        asm volatile("s_waitcnt vmcnt(0)" ::: "memory");
        __builtin_amdgcn_s_barrier();
        __builtin_amdgcn_sched_barrier(0);
    }

    float sc = scale[0];
    #pragma unroll
    for (int mt = 0; mt < 5; ++mt) {
        int o0 = m0 + wm * 80 + mt * 16 + quad * 4;
        #pragma unroll
        for (int nt = 0; nt < 2; ++nt) {
            int n = n0 + wn * 32 + nt * 16 + nl;
            int b = n >> 12, px = n & 4095;
            ushort4 hv = *(const ushort4*)(Cc + ((size_t)(o0 >> 3) * 32768 + n + 16384) * 8 + (o0 & 7));
            size_t base = ((size_t)(b * 320 + o0)) * 4096 + px;
            out[base]            = b2f(hv.x) + sc * acc[mt][nt][0];
            out[base + 4096]     = b2f(hv.y) + sc * acc[mt][nt][1];
            out[base + 2 * 4096] = b2f(hv.z) + sc * acc[mt][nt][2];
            out[base + 3 * 4096] = b2f(hv.w) + sc * acc[mt][nt][3];
        }
    }
#undef STAGEF
}

// ---------------------------------------------------------------------------
extern "C" void kernel_launch(void* const* d_in, const int* in_sizes, int n_in,
                              void* d_out, int out_size, void* d_ws, size_t ws_size,
                              hipStream_t stream)
{
    const float* x      = (const float*)d_in[0];
    const float* weight = (const float*)d_in[1];
    const float* bias   = (const float*)d_in[2];
    const float* w_down = (const float*)d_in[3];
    const float* w_up   = (const float*)d_in[4];
    const float* scale  = (const float*)d_in[5];
    const float* offset = (const float*)d_in[6];
    char* ws = (char*)d_ws;
    unsigned short* Cc    = (unsigned short*)(ws + 0);
    unsigned short* Wr2   = (unsigned short*)(ws + 25165824);
    unsigned short* W2    = (unsigned short*)(ws + 27377664);
    uint32_t*       oI    = (uint32_t*)(ws + 27869184);
    float*          oWt   = (float*)(ws + 28164096);
    unsigned short* Xb    = (unsigned short*)(ws + 28758016);
    unsigned short* Z     = (unsigned short*)(ws + 39909376);
    float* out = (float*)d_out;

    hipLaunchKernelGGL(k_prep, dim3(2194), dim3(256), 0, stream,
                       offset, weight, w_down, w_up, x, oI, oWt, Wr2, W2, Xb);
    hipLaunchKernelGGL(k_zgemm, dim3(128, 18), dim3(256), 0, stream,
                       Xb, Wr2, Z);
    hipLaunchKernelGGL(k_blend, dim3(16, 10, 4), dim3(256), 0, stream,
                       Z, oI, oWt, bias, Cc);
    hipLaunchKernelGGL(k_final, dim3(256, 2), dim3(256), 0, stream,
                       W2, Cc, scale, out);
}

// Round 10
// 180.201 us; speedup vs baseline: 2.4470x; 1.0511x over previous
//
#include <hip/hip_runtime.h>
#include <stdint.h>

// B=4, C=O=320, H=W=64 -> HW=4096, N=16384 (b*4096+px), N2=32768 for Cc.
// Round 10: zgemm A-operand moved out of LDS (global->VGPR from L2/L3-hot
// Wr2, 2.2 MB). r9 zgemm was LDS-pipe-bound: 18 ds_read_b128/wave/step
// (576 cy/CU) vs 40 MFMA (384 cy/CU). A-direct cuts ds_reads to 8
// (256 cy < MFMA) and staging to 4 gl_lds; LDS 72->32 KB -> 3 blk/CU.
// NOT r4's failed variant: there a 94 MB HBM stream evicted the weights
// (FETCH +42 MB); here the whole read set is 12.7 MB, L2/L3-resident
// (FETCH=20 MB in r9 proves it).
//   Z[(k,o), n] = sum_c w[o,c,k] x[c,n]   (GEMM: M=2880, N=16384, K=320)
//   dconv[o,p]  = sum_k sum_t wt_t(k,p) Z_k[o, idx_t(k,p)]      (k_blend)
//   h[o,p]      = sum_k Z_k[o, shift_k(p)] (conv3x3 = free from Z)
//
// Layouts:
//   Wr2 packed-8 K-major: elem(m,c) at ((c>>3)*2880 + m)*8 + (c&7), m=k*320+o.
//   Xb  packed-8:         elem(c,n) at ((c>>3)*16384 + n)*8 + (c&7).
//   Z   packed-8:         elem(m,n) at ((m>>3)*16384 + n)*8 + (m&7).
//   Cc  packed-8:         elem(o,n2) at (o>>3)*32768*8 + n2*8 + (o&7);
//                         n2<16384 dconv+bias, n2>=16384 h+bias.
//   oIdx: 2 u32 per (k,p); oW: float4 weights (validity folded).
//
// ws layout (bytes):
//   Cc 0..25,165,824 | Wr2 ..27,377,664 | W2 ..27,869,184 | oIdx ..28,164,096
//   oWt ..28,753,920 | Xb @28,758,016 | Z @39,909,376 (+94,371,840)

typedef __attribute__((ext_vector_type(4))) float f32x4;
typedef __attribute__((ext_vector_type(8))) short bf16x8;

typedef __attribute__((address_space(1))) const unsigned int uint_as1;
typedef __attribute__((address_space(3))) unsigned int uint_as3;

__device__ __forceinline__ void gl_lds16(const void* g, void* l) {
    __builtin_amdgcn_global_load_lds((uint_as1*)g, (uint_as3*)l, 16, 0, 0);
}

__device__ __forceinline__ unsigned short f2b(float f) {
    union { float f; uint32_t u; } v; v.f = f;
    uint32_t r = (v.u + 0x7FFFu + ((v.u >> 16) & 1u)) >> 16;
    return (unsigned short)r;
}
__device__ __forceinline__ float b2f(unsigned short h) {
    union { uint32_t u; float f; } v; v.u = ((uint32_t)h) << 16;
    return v.f;
}
__device__ __forceinline__ float b2f_lo(uint32_t u) {
    union { uint32_t u; float f; } v; v.u = u << 16;
    return v.f;
}
__device__ __forceinline__ float b2f_hi(uint32_t u) {
    union { uint32_t u; float f; } v; v.u = u & 0xFFFF0000u;
    return v.f;
}
__device__ __forceinline__ uint32_t pack2(float lo, float hi) {
    return (uint32_t)f2b(lo) | ((uint32_t)f2b(hi) << 16);
}

#define TAP8(AC, tv, wvx) \
    AC[0] += wvx * b2f_lo((uint32_t)tv.x); AC[1] += wvx * b2f_hi((uint32_t)tv.x); \
    AC[2] += wvx * b2f_lo((uint32_t)tv.y); AC[3] += wvx * b2f_hi((uint32_t)tv.y); \
    AC[4] += wvx * b2f_lo((uint32_t)tv.z); AC[5] += wvx * b2f_hi((uint32_t)tv.z); \
    AC[6] += wvx * b2f_lo((uint32_t)tv.w); AC[7] += wvx * b2f_hi((uint32_t)tv.w);

// ---------------------------------------------------------------------------
// Fused prep. [0,144) bilinear recs; [144,594) Wr2 (ushort8 coalesced);
// [594,1554) W2 (float4-vectorized reduce); [1554,2194) x->Xb pack.
__global__ __launch_bounds__(256) void k_prep(const float* __restrict__ off,
                                              const float* __restrict__ w,
                                              const float* __restrict__ wd,
                                              const float* __restrict__ wu,
                                              const float* __restrict__ x,
                                              uint32_t* __restrict__ oIdx,
                                              float* __restrict__ oW,
                                              unsigned short* __restrict__ Wr2,
                                              unsigned short* __restrict__ W2,
                                              unsigned short* __restrict__ Xb)
{
    const int bx = blockIdx.x, tid = threadIdx.x;
    if (bx < 144) {
        int gid = bx * 256 + tid;                    // 9*4096 exact
        int k = gid >> 12;
        int p = gid & 4095;
        int i = p >> 6, j = p & 63;
        float dy = off[(2 * k) * 4096 + p];
        float dx = off[(2 * k + 1) * 4096 + p];
        float py = (float)(i - 1 + k / 3) + dy;
        float px = (float)(j - 1 + k % 3) + dx;
        float fy = floorf(py), fx = floorf(px);
        float wy = py - fy, wx = px - fx;
        fy = fminf(fmaxf(fy, -100.f), 100.f);
        fx = fminf(fmaxf(fx, -100.f), 100.f);
        int y0 = (int)fy, x0 = (int)fx;
        float vy0 = (y0 >= 0 && y0 < 64) ? 1.f : 0.f;
        float vy1 = (y0 >= -1 && y0 < 63) ? 1.f : 0.f;
        float vx0 = (x0 >= 0 && x0 < 64) ? 1.f : 0.f;
        float vx1 = (x0 >= -1 && x0 < 63) ? 1.f : 0.f;
        float w00 = (1.f - wy) * (1.f - wx) * vy0 * vx0;
        float w01 = (1.f - wy) * wx * vy0 * vx1;
        float w10 = wy * (1.f - wx) * vy1 * vx0;
        float w11 = wy * wx * vy1 * vx1;
        int ya = min(max(y0, 0), 63), yb = min(max(y0 + 1, 0), 63);
        int xa = min(max(x0, 0), 63), xb = min(max(x0 + 1, 0), 63);
        oIdx[gid * 2 + 0] = (uint32_t)(ya * 64 + xa) | ((uint32_t)(ya * 64 + xb) << 16);
        oIdx[gid * 2 + 1] = (uint32_t)(yb * 64 + xa) | ((uint32_t)(yb * 64 + xb) << 16);
        oW[gid * 4 + 0] = w00;
        oW[gid * 4 + 1] = w01;
        oW[gid * 4 + 2] = w10;
        oW[gid * 4 + 3] = w11;
    } else if (bx < 594) {
        // Wr2: one thread per (cb, m); m = k*320+o; coalesced ushort8 store.
        int gid = (bx - 144) * 256 + tid;            // 40*2880 exact
        int cb = gid / 2880, m = gid - cb * 2880;
        int k = m / 320, o = m - k * 320;
        float v[8];
        #pragma unroll
        for (int cl = 0; cl < 8; ++cl) {
            int c = cb * 8 + cl;
            v[cl] = w[((size_t)o * 320 + c) * 9 + k];
        }
        int4 st;
        st.x = (int)pack2(v[0], v[1]);
        st.y = (int)pack2(v[2], v[3]);
        st.z = (int)pack2(v[4], v[5]);
        st.w = (int)pack2(v[6], v[7]);
        *(int4*)(Wr2 + (size_t)gid * 8) = st;
    } else if (bx < 1554) {
        // W2 = wu @ wd, float4-vectorized over l (4 indep chains).
        int gid = (bx - 594) * 256 + tid;            // 384*640 exact
        int o = gid / 640, kk2 = gid % 640;
        float a0 = 0.f, a1 = 0.f, a2 = 0.f, a3 = 0.f;
        if (o < 320) {
            const float* wuo = wu + (size_t)o * 320;
            for (int l = 0; l < 320; l += 4) {
                float4 u4 = *(const float4*)(wuo + l);
                a0 += u4.x * wd[(size_t)(l + 0) * 640 + kk2];
                a1 += u4.y * wd[(size_t)(l + 1) * 640 + kk2];
                a2 += u4.z * wd[(size_t)(l + 2) * 640 + kk2];
                a3 += u4.w * wd[(size_t)(l + 3) * 640 + kk2];
            }
        }
        W2[(size_t)((kk2 >> 3) * 384 + o) * 8 + (kk2 & 7)] = f2b((a0 + a1) + (a2 + a3));
    } else {
        // Pack x -> Xb (bf16 packed-8): elem(c,n) at ((c>>3)*16384+n)*8+(c&7).
        int bz = bx - 1554;                          // 640 blocks
        int sp = bz & 3, rest = bz >> 2;
        int gl = rest % 40, b = rest / 40;
        const float* xb = x + ((size_t)b * 320 + gl * 8) * 4096;
        unsigned short* xpb = Xb + ((size_t)gl * 16384 + b * 4096) * 8;
        #pragma unroll
        for (int i = 0; i < 4; ++i) {
            int px = sp * 1024 + i * 256 + tid;
            float v0 = xb[0 * 4096 + px], v1 = xb[1 * 4096 + px];
            float v2 = xb[2 * 4096 + px], v3 = xb[3 * 4096 + px];
            float v4 = xb[4 * 4096 + px], v5 = xb[5 * 4096 + px];
            float v6 = xb[6 * 4096 + px], v7 = xb[7 * 4096 + px];
            int4 st;
            st.x = (int)pack2(v0, v1);
            st.y = (int)pack2(v2, v3);
            st.z = (int)pack2(v4, v5);
            st.w = (int)pack2(v6, v7);
            *(int4*)(xpb + (size_t)px * 8) = st;
        }
    }
}

// ---------------------------------------------------------------------------
// Z-GEMM (round 10): A-fragments global->VGPR (L2/L3-hot Wr2); B via dbuf
// LDS (32 KB). M=2880 (18x160), N=16384, K=320 as 5 BK=64 steps. BM=160,
// BN=128, 4 waves 2Mx2N, per-wave 80x64, acc 5x4. 3 blk/CU.
// Per step: A-loads issued FIRST (oldest in vmcnt FIFO -> compiler's wait
// before MFMA resolves at vmcnt(4), leaving B-staging in flight), then
// STAGE_B(s+1), ds_read bf, MFMA, drain, barrier.
__global__ __launch_bounds__(256, 3) void k_zgemm(const unsigned short* __restrict__ Xb,
                                                  const unsigned short* __restrict__ Wr2,
                                                  unsigned short* __restrict__ Z)
{
    __shared__ __align__(16) unsigned short Bs[2][8 * 128 * 8];   // 2 x 16 KB
    const int tid = threadIdx.x;
    const int n0 = blockIdx.x * 128, m0 = blockIdx.y * 160;
    const int lane = tid & 63, w = tid >> 6;
    const int wm = w & 1, wn = w >> 1;
    const int quad = lane >> 4, nl = lane & 15;
    // A-frag lane base: row m0 + wm*80 + nl (+ mt*16), col-block quad
    // (+ s*8 + kc*4). elem at ((cb)*2880 + m)*8 ushorts.
    const unsigned short* Abase = Wr2 + ((size_t)quad * 2880 + m0 + wm * 80 + nl) * 8;

#define STAGE_B(buf, s1) do { \
    _Pragma("unroll") \
    for (int q_ = 0; q_ < 4; ++q_) { \
        int u_ = tid + q_ * 256; \
        int row_ = u_ >> 7, nn_ = n0 + (u_ & 127); \
        gl_lds16(Xb + ((size_t)((s1) * 8 + row_) * 16384 + nn_) * 8, &Bs[buf][u_ * 8]); \
    } \
} while (0)

    f32x4 acc[5][4];
    #pragma unroll
    for (int mt = 0; mt < 5; ++mt)
        #pragma unroll
        for (int nt = 0; nt < 4; ++nt)
            acc[mt][nt] = 0.f;

    STAGE_B(0, 0);
    asm volatile("s_waitcnt vmcnt(0)" ::: "memory");
    __builtin_amdgcn_s_barrier();
    __builtin_amdgcn_sched_barrier(0);

    for (int s = 0; s < 5; ++s) {
        const int p = s & 1, np = p ^ 1;
        // A-loads for this step, issued first.
        bf16x8 a[2][5];
        #pragma unroll
        for (int kc = 0; kc < 2; ++kc)
            #pragma unroll
            for (int mt = 0; mt < 5; ++mt)
                a[kc][mt] = *(const bf16x8*)(Abase
                    + ((size_t)((s * 8 + kc * 4) * 2880) + mt * 16) * 8);
        if (s < 4) STAGE_B(np, s + 1);
        __builtin_amdgcn_sched_barrier(0);
        #pragma unroll
        for (int kc = 0; kc < 2; ++kc) {
            bf16x8 bf[4];
            #pragma unroll
            for (int nt = 0; nt < 4; ++nt)
                bf[nt] = *(const bf16x8*)&Bs[p][((kc * 4 + quad) * 128 + wn * 64 + nt * 16 + nl) * 8];
            #pragma unroll
            for (int mt = 0; mt < 5; ++mt)
                #pragma unroll
                for (int nt = 0; nt < 4; ++nt)
                    acc[mt][nt] = __builtin_amdgcn_mfma_f32_16x16x32_bf16(a[kc][mt], bf[nt], acc[mt][nt], 0, 0, 0);
        }
        asm volatile("s_waitcnt vmcnt(0)" ::: "memory");
        __builtin_amdgcn_s_barrier();
        __builtin_amdgcn_sched_barrier(0);
    }

    // Epilogue: pack to Z (no bias). m index in [0,2880).
    #pragma unroll
    for (int mt = 0; mt < 5; ++mt) {
        int o0m = m0 + wm * 80 + mt * 16 + quad * 4;
        #pragma unroll
        for (int nt = 0; nt < 4; ++nt) {
            int n2 = n0 + wn * 64 + nt * 16 + nl;
            unsigned short* pp = Z + ((size_t)(o0m >> 3) * 16384 + n2) * 8 + (o0m & 7);
            ushort4 st;
            st.x = f2b(acc[mt][nt][0]);
            st.y = f2b(acc[mt][nt][1]);
            st.z = f2b(acc[mt][nt][2]);
            st.w = f2b(acc[mt][nt][3]);
            *(ushort4*)pp = st;
        }
    }
#undef STAGE_B
}

// ---------------------------------------------------------------------------
// Blend: Cc dconv-half = sum_k 4-tap bilinear of Z_k (+bias);
//        Cc h-half     = sum_k shifted Z_k (conv3x3, zero-pad) (+bias).
__global__ __launch_bounds__(256) void k_blend(const unsigned short* __restrict__ Z,
                                               const uint32_t* __restrict__ oIdx,
                                               const float* __restrict__ oW,
                                               const float* __restrict__ bias,
                                               unsigned short* __restrict__ Cc)
{
    const int tid = threadIdx.x;
    const int px = blockIdx.x * 256 + tid;
    const int og0 = blockIdx.y * 4;
    const int b = blockIdx.z;
    const int r = px >> 6, c0 = px & 63;

    uint32_t i0[9], i1[9];
    float4 wv[9];
    int hidx[9];
    float hw[9];
    #pragma unroll
    for (int k = 0; k < 9; ++k) {
        int gi = (k << 12) + px;
        i0[k] = oIdx[gi * 2];
        i1[k] = oIdx[gi * 2 + 1];
        wv[k] = *(const float4*)&oW[(size_t)gi * 4];
        int rr = r + k / 3 - 1, cc = c0 + k % 3 - 1;
        bool valid = (rr >= 0) & (rr < 64) & (cc >= 0) & (cc < 64);
        hidx[k] = valid ? (rr * 64 + cc) : 0;
        hw[k] = valid ? 1.f : 0.f;
    }

    for (int oi = 0; oi < 4; ++oi) {
        int og = og0 + oi;
        float ac[8], ah[8];
        {
            float4 b0 = *(const float4*)&bias[og * 8];
            float4 b1 = *(const float4*)&bias[og * 8 + 4];
            ac[0] = b0.x; ac[1] = b0.y; ac[2] = b0.z; ac[3] = b0.w;
            ac[4] = b1.x; ac[5] = b1.y; ac[6] = b1.z; ac[7] = b1.w;
            #pragma unroll
            for (int j = 0; j < 8; ++j) ah[j] = ac[j];
        }
        #pragma unroll
        for (int k = 0; k < 9; ++k) {
            const unsigned short* Zb = Z + ((size_t)(k * 40 + og) * 16384 + b * 4096) * 8;
            int4 t0 = *(const int4*)(Zb + (size_t)(i0[k] & 0xFFFFu) * 8);
            int4 t1 = *(const int4*)(Zb + (size_t)(i0[k] >> 16) * 8);
            int4 t2 = *(const int4*)(Zb + (size_t)(i1[k] & 0xFFFFu) * 8);
            int4 t3 = *(const int4*)(Zb + (size_t)(i1[k] >> 16) * 8);
            int4 th = *(const int4*)(Zb + (size_t)hidx[k] * 8);
            TAP8(ac, t0, wv[k].x) TAP8(ac, t1, wv[k].y)
            TAP8(ac, t2, wv[k].z) TAP8(ac, t3, wv[k].w)
            TAP8(ah, th, hw[k])
        }
        int4 sd, sh;
        sd.x = (int)pack2(ac[0], ac[1]); sd.y = (int)pack2(ac[2], ac[3]);
        sd.z = (int)pack2(ac[4], ac[5]); sd.w = (int)pack2(ac[6], ac[7]);
        sh.x = (int)pack2(ah[0], ah[1]); sh.y = (int)pack2(ah[2], ah[3]);
        sh.z = (int)pack2(ah[4], ah[5]); sh.w = (int)pack2(ah[6], ah[7]);
        unsigned short* cp = Cc + ((size_t)og * 32768 + b * 4096 + px) * 8;
        *(int4*)cp = sd;
        *(int4*)(cp + 16384 * 8) = sh;
    }
}

// ---------------------------------------------------------------------------
// Final: out = h + scale * (W2 x [dconv; h]), K=640 as 10 BK=64 steps.
// r2-style dbuf 2-phase, BM=160 x BN=64, 4 waves 2Mx2N, per-wave 80x32,
// acc 5x2. LDS 56 KB -> 2 blk/CU; grid 256x2 = 512 = 2/CU exact.
__global__ __launch_bounds__(256) void k_final(const unsigned short* __restrict__ W2,
                                               const unsigned short* __restrict__ Cc,
                                               const float* __restrict__ scale,
                                               float* __restrict__ out)
{
    __shared__ __align__(16) unsigned short As[2][8 * 160 * 8];   // 2 x 20 KB
    __shared__ __align__(16) unsigned short Bs[2][8 * 64 * 8];    // 2 x 8 KB
    const int tid = threadIdx.x;
    const int n0 = blockIdx.x * 64, m0 = blockIdx.y * 160;
    const int lane = tid & 63, w = tid >> 6;
    const int wm = w & 1, wn = w >> 1;
    const int quad = lane >> 4, nl = lane & 15;

#define STAGEF(buf, s1) do { \
    _Pragma("unroll") \
    for (int q_ = 0; q_ < 5; ++q_) { \
        int u_ = tid + q_ * 256; \
        int kq_ = u_ / 160, m_ = u_ - kq_ * 160; \
        gl_lds16(W2 + ((size_t)(((s1) * 8 + kq_) * 384 + m0 + m_)) * 8, &As[buf][u_ * 8]); \
    } \
    { \
        int h_off_ = ((s1) < 5) ? 0 : 16384; \
        int gq_ = ((s1) < 5) ? (s1) * 8 : ((s1) - 5) * 8; \
        _Pragma("unroll") \
        for (int q_ = 0; q_ < 2; ++q_) { \
            int u_ = tid + q_ * 256; \
            int row_ = u_ >> 6, nn_ = n0 + (u_ & 63); \
            gl_lds16(Cc + ((size_t)(gq_ + row_) * 32768 + h_off_ + nn_) * 8, &Bs[buf][u_ * 8]); \
        } \
    } \
} while (0)

    f32x4 acc[5][2];
    #pragma unroll
    for (int mt = 0; mt < 5; ++mt)
        #pragma unroll
        for (int nt = 0; nt < 2; ++nt)
            acc[mt][nt] = 0.f;

    STAGEF(0, 0);
    asm volatile("s_waitcnt vmcnt(0)" ::: "memory");
    __builtin_amdgcn_s_barrier();
    __builtin_amdgcn_sched_barrier(0);

    for (int s = 0; s < 10; ++s) {
        const int p = s & 1, np = p ^ 1;
        if (s < 9) STAGEF(np, s + 1);
        __builtin_amdgcn_sched_barrier(0);
        #pragma unroll
        for (int kc = 0; kc < 2; ++kc) {
            bf16x8 a[5], bf[2];
            #pragma unroll
            for (int mt = 0; mt < 5; ++mt)
                a[mt] = *(const bf16x8*)&As[p][((kc * 4 + quad) * 160 + wm * 80 + mt * 16 + nl) * 8];
            #pragma unroll
            for (int nt = 0; nt < 2; ++nt)
                bf[nt] = *(const bf16x8*)&Bs[p][((kc * 4 + quad) * 64 + wn * 32 + nt * 16 + nl) * 8];
            #pragma unroll
            for (int mt = 0; mt < 5; ++mt)
                #pragma unroll
                for (int nt = 0; nt < 2; ++nt)
                    acc[mt][nt] = __builtin_amdgcn_mfma_f32_16x16x32_bf16(a[mt], bf[nt], acc[mt][nt], 0, 0, 0);
        }
        asm volatile("s_waitcnt vmcnt(0)" ::: "memory");
        __builtin_amdgcn_s_barrier();
        __builtin_amdgcn_sched_barrier(0);
    }

    float sc = scale[0];
    #pragma unroll
    for (int mt = 0; mt < 5; ++mt) {
        int o0 = m0 + wm * 80 + mt * 16 + quad * 4;
        #pragma unroll
        for (int nt = 0; nt < 2; ++nt) {
            int n = n0 + wn * 32 + nt * 16 + nl;
            int b = n >> 12, px = n & 4095;
            ushort4 hv = *(const ushort4*)(Cc + ((size_t)(o0 >> 3) * 32768 + n + 16384) * 8 + (o0 & 7));
            size_t base = ((size_t)(b * 320 + o0)) * 4096 + px;
            out[base]            = b2f(hv.x) + sc * acc[mt][nt][0];
            out[base + 4096]     = b2f(hv.y) + sc * acc[mt][nt][1];
            out[base + 2 * 4096] = b2f(hv.z) + sc * acc[mt][nt][2];
            out[base + 3 * 4096] = b2f(hv.w) + sc * acc[mt][nt][3];
        }
    }
#undef STAGEF
}

// ---------------------------------------------------------------------------
extern "C" void kernel_launch(void* const* d_in, const int* in_sizes, int n_in,
                              void* d_out, int out_size, void* d_ws, size_t ws_size,
                              hipStream_t stream)
{
    const float* x      = (const float*)d_in[0];
    const float* weight = (const float*)d_in[1];
    const float* bias   = (const float*)d_in[2];
    const float* w_down = (const float*)d_in[3];
    const float* w_up   = (const float*)d_in[4];
    const float* scale  = (const float*)d_in[5];
    const float* offset = (const float*)d_in[6];
    char* ws = (char*)d_ws;
    unsigned short* Cc    = (unsigned short*)(ws + 0);
    unsigned short* Wr2   = (unsigned short*)(ws + 25165824);
    unsigned short* W2    = (unsigned short*)(ws + 27377664);
    uint32_t*       oI    = (uint32_t*)(ws + 27869184);
    float*          oWt   = (float*)(ws + 28164096);
    unsigned short* Xb    = (unsigned short*)(ws + 28758016);
    unsigned short* Z     = (unsigned short*)(ws + 39909376);
    float* out = (float*)d_out;

    hipLaunchKernelGGL(k_prep, dim3(2194), dim3(256), 0, stream,
                       offset, weight, w_down, w_up, x, oI, oWt, Wr2, W2, Xb);
    hipLaunchKernelGGL(k_zgemm, dim3(128, 18), dim3(256), 0, stream,
                       Xb, Wr2, Z);
    hipLaunchKernelGGL(k_blend, dim3(16, 10, 4), dim3(256), 0, stream,
                       Z, oI, oWt, bias, Cc);
    hipLaunchKernelGGL(k_final, dim3(256, 2), dim3(256), 0, stream,
                       W2, Cc, scale, out);
}

// Round 11
// 177.633 us; speedup vs baseline: 2.4824x; 1.0145x over previous
//
#include <hip/hip_runtime.h>
#include <stdint.h>

// B=4, C=O=320, H=W=64 -> HW=4096, N=16384 (b*4096+px), N2=32768 for Cc.
// Round 11: k_blend occupancy fix. r10 blend was latency-bound (Occ 16.8%,
// VALU 19%, HBM 19% -- 4x above roofline): 640 blocks = 2.5/CU with 4
// serial og-groups of 45 dependent gathers each. Now 1 og per thread,
// grid (16,40,4) = 2560 blocks = 10/CU (fills the 32-wave/CU cap);
// VGPR drops (no 4-og state). Rec re-reads (+105 MB logical) are L2-hot.
// prep/zgemm/final unchanged (r10-verified).
//   Z[(k,o), n] = sum_c w[o,c,k] x[c,n]   (GEMM: M=2880, N=16384, K=320)
//   dconv[o,p]  = sum_k sum_t wt_t(k,p) Z_k[o, idx_t(k,p)]      (k_blend)
//   h[o,p]      = sum_k Z_k[o, shift_k(p)] (conv3x3 = free from Z)
//
// Layouts:
//   Wr2 packed-8 K-major: elem(m,c) at ((c>>3)*2880 + m)*8 + (c&7), m=k*320+o.
//   Xb  packed-8:         elem(c,n) at ((c>>3)*16384 + n)*8 + (c&7).
//   Z   packed-8:         elem(m,n) at ((m>>3)*16384 + n)*8 + (m&7).
//   Cc  packed-8:         elem(o,n2) at (o>>3)*32768*8 + n2*8 + (o&7);
//                         n2<16384 dconv+bias, n2>=16384 h+bias.
//   oIdx: 2 u32 per (k,p); oW: float4 weights (validity folded).
//
// ws layout (bytes):
//   Cc 0..25,165,824 | Wr2 ..27,377,664 | W2 ..27,869,184 | oIdx ..28,164,096
//   oWt ..28,753,920 | Xb @28,758,016 | Z @39,909,376 (+94,371,840)

typedef __attribute__((ext_vector_type(4))) float f32x4;
typedef __attribute__((ext_vector_type(8))) short bf16x8;

typedef __attribute__((address_space(1))) const unsigned int uint_as1;
typedef __attribute__((address_space(3))) unsigned int uint_as3;

__device__ __forceinline__ void gl_lds16(const void* g, void* l) {
    __builtin_amdgcn_global_load_lds((uint_as1*)g, (uint_as3*)l, 16, 0, 0);
}

__device__ __forceinline__ unsigned short f2b(float f) {
    union { float f; uint32_t u; } v; v.f = f;
    uint32_t r = (v.u + 0x7FFFu + ((v.u >> 16) & 1u)) >> 16;
    return (unsigned short)r;
}
__device__ __forceinline__ float b2f(unsigned short h) {
    union { uint32_t u; float f; } v; v.u = ((uint32_t)h) << 16;
    return v.f;
}
__device__ __forceinline__ float b2f_lo(uint32_t u) {
    union { uint32_t u; float f; } v; v.u = u << 16;
    return v.f;
}
__device__ __forceinline__ float b2f_hi(uint32_t u) {
    union { uint32_t u; float f; } v; v.u = u & 0xFFFF0000u;
    return v.f;
}
__device__ __forceinline__ uint32_t pack2(float lo, float hi) {
    return (uint32_t)f2b(lo) | ((uint32_t)f2b(hi) << 16);
}

#define TAP8(AC, tv, wvx) \
    AC[0] += wvx * b2f_lo((uint32_t)tv.x); AC[1] += wvx * b2f_hi((uint32_t)tv.x); \
    AC[2] += wvx * b2f_lo((uint32_t)tv.y); AC[3] += wvx * b2f_hi((uint32_t)tv.y); \
    AC[4] += wvx * b2f_lo((uint32_t)tv.z); AC[5] += wvx * b2f_hi((uint32_t)tv.z); \
    AC[6] += wvx * b2f_lo((uint32_t)tv.w); AC[7] += wvx * b2f_hi((uint32_t)tv.w);

// ---------------------------------------------------------------------------
// Fused prep. [0,144) bilinear recs; [144,594) Wr2 (ushort8 coalesced);
// [594,1554) W2 (float4-vectorized reduce); [1554,2194) x->Xb pack.
__global__ __launch_bounds__(256) void k_prep(const float* __restrict__ off,
                                              const float* __restrict__ w,
                                              const float* __restrict__ wd,
                                              const float* __restrict__ wu,
                                              const float* __restrict__ x,
                                              uint32_t* __restrict__ oIdx,
                                              float* __restrict__ oW,
                                              unsigned short* __restrict__ Wr2,
                                              unsigned short* __restrict__ W2,
                                              unsigned short* __restrict__ Xb)
{
    const int bx = blockIdx.x, tid = threadIdx.x;
    if (bx < 144) {
        int gid = bx * 256 + tid;                    // 9*4096 exact
        int k = gid >> 12;
        int p = gid & 4095;
        int i = p >> 6, j = p & 63;
        float dy = off[(2 * k) * 4096 + p];
        float dx = off[(2 * k + 1) * 4096 + p];
        float py = (float)(i - 1 + k / 3) + dy;
        float px = (float)(j - 1 + k % 3) + dx;
        float fy = floorf(py), fx = floorf(px);
        float wy = py - fy, wx = px - fx;
        fy = fminf(fmaxf(fy, -100.f), 100.f);
        fx = fminf(fmaxf(fx, -100.f), 100.f);
        int y0 = (int)fy, x0 = (int)fx;
        float vy0 = (y0 >= 0 && y0 < 64) ? 1.f : 0.f;
        float vy1 = (y0 >= -1 && y0 < 63) ? 1.f : 0.f;
        float vx0 = (x0 >= 0 && x0 < 64) ? 1.f : 0.f;
        float vx1 = (x0 >= -1 && x0 < 63) ? 1.f : 0.f;
        float w00 = (1.f - wy) * (1.f - wx) * vy0 * vx0;
        float w01 = (1.f - wy) * wx * vy0 * vx1;
        float w10 = wy * (1.f - wx) * vy1 * vx0;
        float w11 = wy * wx * vy1 * vx1;
        int ya = min(max(y0, 0), 63), yb = min(max(y0 + 1, 0), 63);
        int xa = min(max(x0, 0), 63), xb = min(max(x0 + 1, 0), 63);
        oIdx[gid * 2 + 0] = (uint32_t)(ya * 64 + xa) | ((uint32_t)(ya * 64 + xb) << 16);
        oIdx[gid * 2 + 1] = (uint32_t)(yb * 64 + xa) | ((uint32_t)(yb * 64 + xb) << 16);
        oW[gid * 4 + 0] = w00;
        oW[gid * 4 + 1] = w01;
        oW[gid * 4 + 2] = w10;
        oW[gid * 4 + 3] = w11;
    } else if (bx < 594) {
        // Wr2: one thread per (cb, m); m = k*320+o; coalesced ushort8 store.
        int gid = (bx - 144) * 256 + tid;            // 40*2880 exact
        int cb = gid / 2880, m = gid - cb * 2880;
        int k = m / 320, o = m - k * 320;
        float v[8];
        #pragma unroll
        for (int cl = 0; cl < 8; ++cl) {
            int c = cb * 8 + cl;
            v[cl] = w[((size_t)o * 320 + c) * 9 + k];
        }
        int4 st;
        st.x = (int)pack2(v[0], v[1]);
        st.y = (int)pack2(v[2], v[3]);
        st.z = (int)pack2(v[4], v[5]);
        st.w = (int)pack2(v[6], v[7]);
        *(int4*)(Wr2 + (size_t)gid * 8) = st;
    } else if (bx < 1554) {
        // W2 = wu @ wd, float4-vectorized over l (4 indep chains).
        int gid = (bx - 594) * 256 + tid;            // 384*640 exact
        int o = gid / 640, kk2 = gid % 640;
        float a0 = 0.f, a1 = 0.f, a2 = 0.f, a3 = 0.f;
        if (o < 320) {
            const float* wuo = wu + (size_t)o * 320;
            for (int l = 0; l < 320; l += 4) {
                float4 u4 = *(const float4*)(wuo + l);
                a0 += u4.x * wd[(size_t)(l + 0) * 640 + kk2];
                a1 += u4.y * wd[(size_t)(l + 1) * 640 + kk2];
                a2 += u4.z * wd[(size_t)(l + 2) * 640 + kk2];
                a3 += u4.w * wd[(size_t)(l + 3) * 640 + kk2];
            }
        }
        W2[(size_t)((kk2 >> 3) * 384 + o) * 8 + (kk2 & 7)] = f2b((a0 + a1) + (a2 + a3));
    } else {
        // Pack x -> Xb (bf16 packed-8): elem(c,n) at ((c>>3)*16384+n)*8+(c&7).
        int bz = bx - 1554;                          // 640 blocks
        int sp = bz & 3, rest = bz >> 2;
        int gl = rest % 40, b = rest / 40;
        const float* xb = x + ((size_t)b * 320 + gl * 8) * 4096;
        unsigned short* xpb = Xb + ((size_t)gl * 16384 + b * 4096) * 8;
        #pragma unroll
        for (int i = 0; i < 4; ++i) {
            int px = sp * 1024 + i * 256 + tid;
            float v0 = xb[0 * 4096 + px], v1 = xb[1 * 4096 + px];
            float v2 = xb[2 * 4096 + px], v3 = xb[3 * 4096 + px];
            float v4 = xb[4 * 4096 + px], v5 = xb[5 * 4096 + px];
            float v6 = xb[6 * 4096 + px], v7 = xb[7 * 4096 + px];
            int4 st;
            st.x = (int)pack2(v0, v1);
            st.y = (int)pack2(v2, v3);
            st.z = (int)pack2(v4, v5);
            st.w = (int)pack2(v6, v7);
            *(int4*)(xpb + (size_t)px * 8) = st;
        }
    }
}

// ---------------------------------------------------------------------------
// Z-GEMM (r10-verified): A-fragments global->VGPR (L2/L3-hot Wr2); B via
// dbuf LDS (32 KB). M=2880 (18x160), N=16384, K=320 as 5 BK=64 steps.
// BM=160, BN=128, 4 waves 2Mx2N, per-wave 80x64, acc 5x4. 3 blk/CU.
__global__ __launch_bounds__(256, 3) void k_zgemm(const unsigned short* __restrict__ Xb,
                                                  const unsigned short* __restrict__ Wr2,
                                                  unsigned short* __restrict__ Z)
{
    __shared__ __align__(16) unsigned short Bs[2][8 * 128 * 8];   // 2 x 16 KB
    const int tid = threadIdx.x;
    const int n0 = blockIdx.x * 128, m0 = blockIdx.y * 160;
    const int lane = tid & 63, w = tid >> 6;
    const int wm = w & 1, wn = w >> 1;
    const int quad = lane >> 4, nl = lane & 15;
    const unsigned short* Abase = Wr2 + ((size_t)quad * 2880 + m0 + wm * 80 + nl) * 8;

#define STAGE_B(buf, s1) do { \
    _Pragma("unroll") \
    for (int q_ = 0; q_ < 4; ++q_) { \
        int u_ = tid + q_ * 256; \
        int row_ = u_ >> 7, nn_ = n0 + (u_ & 127); \
        gl_lds16(Xb + ((size_t)((s1) * 8 + row_) * 16384 + nn_) * 8, &Bs[buf][u_ * 8]); \
    } \
} while (0)

    f32x4 acc[5][4];
    #pragma unroll
    for (int mt = 0; mt < 5; ++mt)
        #pragma unroll
        for (int nt = 0; nt < 4; ++nt)
            acc[mt][nt] = 0.f;

    STAGE_B(0, 0);
    asm volatile("s_waitcnt vmcnt(0)" ::: "memory");
    __builtin_amdgcn_s_barrier();
    __builtin_amdgcn_sched_barrier(0);

    for (int s = 0; s < 5; ++s) {
        const int p = s & 1, np = p ^ 1;
        bf16x8 a[2][5];
        #pragma unroll
        for (int kc = 0; kc < 2; ++kc)
            #pragma unroll
            for (int mt = 0; mt < 5; ++mt)
                a[kc][mt] = *(const bf16x8*)(Abase
                    + ((size_t)((s * 8 + kc * 4) * 2880) + mt * 16) * 8);
        if (s < 4) STAGE_B(np, s + 1);
        __builtin_amdgcn_sched_barrier(0);
        #pragma unroll
        for (int kc = 0; kc < 2; ++kc) {
            bf16x8 bf[4];
            #pragma unroll
            for (int nt = 0; nt < 4; ++nt)
                bf[nt] = *(const bf16x8*)&Bs[p][((kc * 4 + quad) * 128 + wn * 64 + nt * 16 + nl) * 8];
            #pragma unroll
            for (int mt = 0; mt < 5; ++mt)
                #pragma unroll
                for (int nt = 0; nt < 4; ++nt)
                    acc[mt][nt] = __builtin_amdgcn_mfma_f32_16x16x32_bf16(a[kc][mt], bf[nt], acc[mt][nt], 0, 0, 0);
        }
        asm volatile("s_waitcnt vmcnt(0)" ::: "memory");
        __builtin_amdgcn_s_barrier();
        __builtin_amdgcn_sched_barrier(0);
    }

    // Epilogue: pack to Z (no bias). m index in [0,2880).
    #pragma unroll
    for (int mt = 0; mt < 5; ++mt) {
        int o0m = m0 + wm * 80 + mt * 16 + quad * 4;
        #pragma unroll
        for (int nt = 0; nt < 4; ++nt) {
            int n2 = n0 + wn * 64 + nt * 16 + nl;
            unsigned short* pp = Z + ((size_t)(o0m >> 3) * 16384 + n2) * 8 + (o0m & 7);
            ushort4 st;
            st.x = f2b(acc[mt][nt][0]);
            st.y = f2b(acc[mt][nt][1]);
            st.z = f2b(acc[mt][nt][2]);
            st.w = f2b(acc[mt][nt][3]);
            *(ushort4*)pp = st;
        }
    }
#undef STAGE_B
}

// ---------------------------------------------------------------------------
// Blend (round 11): 1 og per thread, grid (16, 40, 4) = 2560 blocks =
// 10 blk/CU (was 640 = 2.5/CU with a serial 4-og loop -> latency-bound).
// Cc dconv-half = sum_k 4-tap bilinear of Z_k (+bias);
// Cc h-half     = sum_k shifted Z_k (conv3x3, zero-pad) (+bias).
__global__ __launch_bounds__(256) void k_blend(const unsigned short* __restrict__ Z,
                                               const uint32_t* __restrict__ oIdx,
                                               const float* __restrict__ oW,
                                               const float* __restrict__ bias,
                                               unsigned short* __restrict__ Cc)
{
    const int tid = threadIdx.x;
    const int px = blockIdx.x * 256 + tid;
    const int og = blockIdx.y;
    const int b = blockIdx.z;
    const int r = px >> 6, c0 = px & 63;

    float ac[8], ah[8];
    {
        float4 b0 = *(const float4*)&bias[og * 8];
        float4 b1 = *(const float4*)&bias[og * 8 + 4];
        ac[0] = b0.x; ac[1] = b0.y; ac[2] = b0.z; ac[3] = b0.w;
        ac[4] = b1.x; ac[5] = b1.y; ac[6] = b1.z; ac[7] = b1.w;
        #pragma unroll
        for (int j = 0; j < 8; ++j) ah[j] = ac[j];
    }
    #pragma unroll
    for (int k = 0; k < 9; ++k) {
        int gi = (k << 12) + px;
        uint32_t i0 = oIdx[gi * 2];
        uint32_t i1 = oIdx[gi * 2 + 1];
        float4 wv = *(const float4*)&oW[(size_t)gi * 4];
        int rr = r + k / 3 - 1, cc = c0 + k % 3 - 1;
        bool valid = (rr >= 0) & (rr < 64) & (cc >= 0) & (cc < 64);
        int hidx = valid ? (rr * 64 + cc) : 0;
        float hw = valid ? 1.f : 0.f;
        const unsigned short* Zb = Z + ((size_t)(k * 40 + og) * 16384 + b * 4096) * 8;
        int4 t0 = *(const int4*)(Zb + (size_t)(i0 & 0xFFFFu) * 8);
        int4 t1 = *(const int4*)(Zb + (size_t)(i0 >> 16) * 8);
        int4 t2 = *(const int4*)(Zb + (size_t)(i1 & 0xFFFFu) * 8);
        int4 t3 = *(const int4*)(Zb + (size_t)(i1 >> 16) * 8);
        int4 th = *(const int4*)(Zb + (size_t)hidx * 8);
        TAP8(ac, t0, wv.x) TAP8(ac, t1, wv.y)
        TAP8(ac, t2, wv.z) TAP8(ac, t3, wv.w)
        TAP8(ah, th, hw)
    }
    int4 sd, sh;
    sd.x = (int)pack2(ac[0], ac[1]); sd.y = (int)pack2(ac[2], ac[3]);
    sd.z = (int)pack2(ac[4], ac[5]); sd.w = (int)pack2(ac[6], ac[7]);
    sh.x = (int)pack2(ah[0], ah[1]); sh.y = (int)pack2(ah[2], ah[3]);
    sh.z = (int)pack2(ah[4], ah[5]); sh.w = (int)pack2(ah[6], ah[7]);
    unsigned short* cp = Cc + ((size_t)og * 32768 + b * 4096 + px) * 8;
    *(int4*)cp = sd;
    *(int4*)(cp + 16384 * 8) = sh;
}

// ---------------------------------------------------------------------------
// Final: out = h + scale * (W2 x [dconv; h]), K=640 as 10 BK=64 steps.
// r2-style dbuf 2-phase, BM=160 x BN=64, 4 waves 2Mx2N, per-wave 80x32,
// acc 5x2. LDS 56 KB -> 2 blk/CU; grid 256x2 = 512 = 2/CU exact.
__global__ __launch_bounds__(256) void k_final(const unsigned short* __restrict__ W2,
                                               const unsigned short* __restrict__ Cc,
                                               const float* __restrict__ scale,
                                               float* __restrict__ out)
{
    __shared__ __align__(16) unsigned short As[2][8 * 160 * 8];   // 2 x 20 KB
    __shared__ __align__(16) unsigned short Bs[2][8 * 64 * 8];    // 2 x 8 KB
    const int tid = threadIdx.x;
    const int n0 = blockIdx.x * 64, m0 = blockIdx.y * 160;
    const int lane = tid & 63, w = tid >> 6;
    const int wm = w & 1, wn = w >> 1;
    const int quad = lane >> 4, nl = lane & 15;

#define STAGEF(buf, s1) do { \
    _Pragma("unroll") \
    for (int q_ = 0; q_ < 5; ++q_) { \
        int u_ = tid + q_ * 256; \
        int kq_ = u_ / 160, m_ = u_ - kq_ * 160; \
        gl_lds16(W2 + ((size_t)(((s1) * 8 + kq_) * 384 + m0 + m_)) * 8, &As[buf][u_ * 8]); \
    } \
    { \
        int h_off_ = ((s1) < 5) ? 0 : 16384; \
        int gq_ = ((s1) < 5) ? (s1) * 8 : ((s1) - 5) * 8; \
        _Pragma("unroll") \
        for (int q_ = 0; q_ < 2; ++q_) { \
            int u_ = tid + q_ * 256; \
            int row_ = u_ >> 6, nn_ = n0 + (u_ & 63); \
            gl_lds16(Cc + ((size_t)(gq_ + row_) * 32768 + h_off_ + nn_) * 8, &Bs[buf][u_ * 8]); \
        } \
    } \
} while (0)

    f32x4 acc[5][2];
    #pragma unroll
    for (int mt = 0; mt < 5; ++mt)
        #pragma unroll
        for (int nt = 0; nt < 2; ++nt)
            acc[mt][nt] = 0.f;

    STAGEF(0, 0);
    asm volatile("s_waitcnt vmcnt(0)" ::: "memory");
    __builtin_amdgcn_s_barrier();
    __builtin_amdgcn_sched_barrier(0);

    for (int s = 0; s < 10; ++s) {
        const int p = s & 1, np = p ^ 1;
        if (s < 9) STAGEF(np, s + 1);
        __builtin_amdgcn_sched_barrier(0);
        #pragma unroll
        for (int kc = 0; kc < 2; ++kc) {
            bf16x8 a[5], bf[2];
            #pragma unroll
            for (int mt = 0; mt < 5; ++mt)
                a[mt] = *(const bf16x8*)&As[p][((kc * 4 + quad) * 160 + wm * 80 + mt * 16 + nl) * 8];
            #pragma unroll
            for (int nt = 0; nt < 2; ++nt)
                bf[nt] = *(const bf16x8*)&Bs[p][((kc * 4 + quad) * 64 + wn * 32 + nt * 16 + nl) * 8];
            #pragma unroll
            for (int mt = 0; mt < 5; ++mt)
                #pragma unroll
                for (int nt = 0; nt < 2; ++nt)
                    acc[mt][nt] = __builtin_amdgcn_mfma_f32_16x16x32_bf16(a[mt], bf[nt], acc[mt][nt], 0, 0, 0);
        }
        asm volatile("s_waitcnt vmcnt(0)" ::: "memory");
        __builtin_amdgcn_s_barrier();
        __builtin_amdgcn_sched_barrier(0);
    }

    float sc = scale[0];
    #pragma unroll
    for (int mt = 0; mt < 5; ++mt) {
        int o0 = m0 + wm * 80 + mt * 16 + quad * 4;
        #pragma unroll
        for (int nt = 0; nt < 2; ++nt) {
            int n = n0 + wn * 32 + nt * 16 + nl;
            int b = n >> 12, px = n & 4095;
            ushort4 hv = *(const ushort4*)(Cc + ((size_t)(o0 >> 3) * 32768 + n + 16384) * 8 + (o0 & 7));
            size_t base = ((size_t)(b * 320 + o0)) * 4096 + px;
            out[base]            = b2f(hv.x) + sc * acc[mt][nt][0];
            out[base + 4096]     = b2f(hv.y) + sc * acc[mt][nt][1];
            out[base + 2 * 4096] = b2f(hv.z) + sc * acc[mt][nt][2];
            out[base + 3 * 4096] = b2f(hv.w) + sc * acc[mt][nt][3];
        }
    }
#undef STAGEF
}

// ---------------------------------------------------------------------------
extern "C" void kernel_launch(void* const* d_in, const int* in_sizes, int n_in,
                              void* d_out, int out_size, void* d_ws, size_t ws_size,
                              hipStream_t stream)
{
    const float* x      = (const float*)d_in[0];
    const float* weight = (const float*)d_in[1];
    const float* bias   = (const float*)d_in[2];
    const float* w_down = (const float*)d_in[3];
    const float* w_up   = (const float*)d_in[4];
    const float* scale  = (const float*)d_in[5];
    const float* offset = (const float*)d_in[6];
    char* ws = (char*)d_ws;
    unsigned short* Cc    = (unsigned short*)(ws + 0);
    unsigned short* Wr2   = (unsigned short*)(ws + 25165824);
    unsigned short* W2    = (unsigned short*)(ws + 27377664);
    uint32_t*       oI    = (uint32_t*)(ws + 27869184);
    float*          oWt   = (float*)(ws + 28164096);
    unsigned short* Xb    = (unsigned short*)(ws + 28758016);
    unsigned short* Z     = (unsigned short*)(ws + 39909376);
    float* out = (float*)d_out;

    hipLaunchKernelGGL(k_prep, dim3(2194), dim3(256), 0, stream,
                       offset, weight, w_down, w_up, x, oI, oWt, Wr2, W2, Xb);
    hipLaunchKernelGGL(k_zgemm, dim3(128, 18), dim3(256), 0, stream,
                       Xb, Wr2, Z);
    hipLaunchKernelGGL(k_blend, dim3(16, 40, 4), dim3(256), 0, stream,
                       Z, oI, oWt, bias, Cc);
    hipLaunchKernelGGL(k_final, dim3(256, 2), dim3(256), 0, stream,
                       W2, Cc, scale, out);
}